// Round 1
// baseline (2529.759 us; speedup 1.0000x reference)
//
#include <hip/hip_runtime.h>
#include <math.h>

#define BQ 1024
#define FDIM 128
#define DDIM 256
#define DIDIM 512
#define NTOT 100000
#define CTX 96

// ---------- K0: fused encoder weights: Wf = W_lin@W_K, bf = b_lin@W_K + b_K ----------
__global__ __launch_bounds__(256) void k_fuse(
    const float* __restrict__ Wlin, const float* __restrict__ blin,
    const float* __restrict__ WK, const float* __restrict__ bK,
    float* __restrict__ Wf, float* __restrict__ bf)
{
    int i = blockIdx.x, j = threadIdx.x;
    if (i < FDIM) {
        float acc = 0.f;
        for (int l = 0; l < DDIM; ++l) acc += Wlin[i*DDIM + l] * WK[l*DDIM + j];
        Wf[i*DDIM + j] = acc;
    } else {
        float acc = bK[j];
        for (int l = 0; l < DDIM; ++l) acc += blin[l] * WK[l*DDIM + j];
        bf[j] = acc;
    }
}

// ---------- K1: per query row: x_enc = x@W_lin + b_lin ; k = x@Wf + bf ----------
__global__ __launch_bounds__(256) void k_query(
    const float* __restrict__ x, const float* __restrict__ Wlin,
    const float* __restrict__ blin, const float* __restrict__ Wf,
    const float* __restrict__ bf,
    float* __restrict__ xenc, float* __restrict__ kq)
{
    __shared__ float xs[FDIM];
    int b = blockIdx.x, j = threadIdx.x;
    if (j < FDIM) xs[j] = x[(size_t)b*FDIM + j];
    __syncthreads();
    float a0 = blin[j], a1 = bf[j];
    for (int l = 0; l < FDIM; ++l) {
        float xv = xs[l];
        a0 += xv * Wlin[l*DDIM + j];
        a1 += xv * Wf[l*DDIM + j];
    }
    xenc[(size_t)b*DDIM + j] = a0;
    kq[(size_t)b*DDIM + j] = a1;
}

// ---------- K1b: kp[b] = Wf @ k[b]  (128-dim projected query) ----------
__global__ __launch_bounds__(128) void k_kp(
    const float* __restrict__ kq, const float* __restrict__ Wf, float* __restrict__ kp)
{
    __shared__ float ks[DDIM];
    int b = blockIdx.x, l = threadIdx.x;
    ks[l] = kq[(size_t)b*DDIM + l];
    ks[l+128] = kq[(size_t)b*DDIM + l + 128];
    __syncthreads();
    float a = 0.f;
    for (int d = 0; d < DDIM; ++d) a += Wf[l*DDIM + d] * ks[d];
    kp[(size_t)b*FDIM + l] = a;
}

// ---------- K2: ki_all = cand@Wf + bf, and ki_norm ----------
__global__ __launch_bounds__(256) void k_cand(
    const float* __restrict__ cand, const float* __restrict__ Wf,
    const float* __restrict__ bf, float* __restrict__ ki, float* __restrict__ kinorm)
{
    __shared__ float cs[8][FDIM];
    __shared__ float red[256];
    int n0 = blockIdx.x * 8, j = threadIdx.x;
    for (int t = 0; t < 4; ++t) {
        int e = j + t*256; int r = e >> 7, c = e & 127;
        int n = n0 + r;
        cs[r][c] = (n < NTOT) ? cand[(size_t)n*FDIM + c] : 0.f;
    }
    __syncthreads();
    float acc[8];
    #pragma unroll
    for (int r = 0; r < 8; ++r) acc[r] = bf[j];
    for (int l = 0; l < FDIM; ++l) {
        float w = Wf[l*DDIM + j];
        #pragma unroll
        for (int r = 0; r < 8; ++r) acc[r] += cs[r][l] * w;
    }
    #pragma unroll
    for (int r = 0; r < 8; ++r) {
        int n = n0 + r;
        if (n < NTOT) ki[(size_t)n*DDIM + j] = acc[r];
    }
    for (int r = 0; r < 8; ++r) {
        red[j] = acc[r]*acc[r];
        __syncthreads();
        for (int s2 = 128; s2 > 0; s2 >>= 1) { if (j < s2) red[j] += red[j+s2]; __syncthreads(); }
        if (j == 0 && (n0 + r) < NTOT) kinorm[n0+r] = red[0];
        __syncthreads();
    }
}

// ---------- K3: score GEMM  s[b][j] = kinorm[n] - 2 * cand_n . kp_b ----------
__global__ __launch_bounds__(256) void k_dist(
    const float* __restrict__ cand, const float* __restrict__ kp,
    const float* __restrict__ kinorm, float* __restrict__ s, int n0, int NC)
{
    __shared__ float As[64][68];
    __shared__ float Bs[64][68];
    int bn = blockIdx.x * 64;
    int bm = blockIdx.y * 64;
    int tid = threadIdx.x;
    int tm = tid >> 4, tn = tid & 15;
    float acc[4][4] = {};
    for (int kc = 0; kc < FDIM; kc += 64) {
        #pragma unroll
        for (int t = 0; t < 16; ++t) {
            int e = tid + t*256; int r = e >> 6, c = e & 63;
            As[r][c] = kp[(size_t)(bm + r)*FDIM + kc + c];
            int n = n0 + bn + r;
            Bs[r][c] = (n < NTOT) ? cand[(size_t)n*FDIM + kc + c] : 0.f;
        }
        __syncthreads();
        #pragma unroll 4
        for (int k4 = 0; k4 < 16; ++k4) {
            float4 a4[4], b4[4];
            #pragma unroll
            for (int i = 0; i < 4; ++i) a4[i] = *reinterpret_cast<const float4*>(&As[tm + 16*i][k4*4]);
            #pragma unroll
            for (int j = 0; j < 4; ++j) b4[j] = *reinterpret_cast<const float4*>(&Bs[tn + 16*j][k4*4]);
            #pragma unroll
            for (int i = 0; i < 4; ++i)
                #pragma unroll
                for (int j = 0; j < 4; ++j)
                    acc[i][j] += a4[i].x*b4[j].x + a4[i].y*b4[j].y + a4[i].z*b4[j].z + a4[i].w*b4[j].w;
        }
        __syncthreads();
    }
    #pragma unroll
    for (int i = 0; i < 4; ++i) {
        int m = bm + tm + 16*i;
        #pragma unroll
        for (int j = 0; j < 4; ++j) {
            int cj = bn + tn + 16*j;
            int n = n0 + cj;
            s[(size_t)m*NC + cj] = (n < NTOT) ? (kinorm[n] - 2.f*acc[i][j]) : INFINITY;
        }
    }
}

// ---------- K4: streaming top-96 (smallest) merge per row ----------
__device__ __forceinline__ void topk_merge(float* sv, int* si, int cntv, int tid)
{
    int nvalid = CTX + cntv;
    int size = 128;
    while (size < nvalid) size <<= 1;
    for (int i = nvalid + tid; i < size; i += 256) { sv[i] = INFINITY; si[i] = -1; }
    __syncthreads();
    for (int k2 = 2; k2 <= size; k2 <<= 1) {
        for (int jj = k2 >> 1; jj > 0; jj >>= 1) {
            for (int i = tid; i < size; i += 256) {
                int ix = i ^ jj;
                if (ix > i) {
                    bool up = ((i & k2) == 0);
                    float a = sv[i], b2 = sv[ix];
                    if ((a > b2) == up) {
                        sv[i] = b2; sv[ix] = a;
                        int t2 = si[i]; si[i] = si[ix]; si[ix] = t2;
                    }
                }
            }
            __syncthreads();
        }
    }
}

__global__ __launch_bounds__(256) void k_select(
    const float* __restrict__ s, float* __restrict__ runV, int* __restrict__ runI,
    int n0, int NC, int init)
{
    __shared__ float sv[4096];
    __shared__ int   si[4096];
    __shared__ float thresh;
    __shared__ int cnt;
    int b = blockIdx.x, tid = threadIdx.x;
    if (init) {
        for (int i = tid; i < CTX; i += 256) { sv[i] = INFINITY; si[i] = 0; }
    } else {
        for (int i = tid; i < CTX; i += 256) { sv[i] = runV[b*CTX + i]; si[i] = runI[b*CTX + i]; }
    }
    if (tid == 0) { cnt = 0; }
    __syncthreads();
    if (tid == 0) thresh = sv[CTX-1];
    __syncthreads();
    const float* row = s + (size_t)b * NC;
    for (int base = 0; base < NC; base += 1024) {
        int j = base + tid*4;
        if (j < NC) {
            float4 v4 = *reinterpret_cast<const float4*>(row + j);
            float th = thresh;
            float vv[4] = {v4.x, v4.y, v4.z, v4.w};
            #pragma unroll
            for (int q = 0; q < 4; ++q) {
                if (vv[q] < th) {
                    int p = atomicAdd(&cnt, 1);
                    sv[CTX + p] = vv[q]; si[CTX + p] = n0 + j + q;
                }
            }
        }
        __syncthreads();
        int cv = cnt;
        if (cv > 1024) {
            topk_merge(sv, si, cv, tid);
            if (tid == 0) { thresh = sv[CTX-1]; cnt = 0; }
            __syncthreads();
        }
    }
    __syncthreads();
    int cv = cnt;
    if (cv > 0) topk_merge(sv, si, cv, tid);
    __syncthreads();
    for (int i = tid; i < CTX; i += 256) { runV[b*CTX + i] = sv[i]; runI[b*CTX + i] = si[i]; }
}

// ---------- K5: softmax weights over selected scores + weighted y ----------
__global__ __launch_bounds__(128) void k_weights(
    const float* __restrict__ runV, const int* __restrict__ runI,
    const float* __restrict__ candy, float* __restrict__ wts, float* __restrict__ wy)
{
    __shared__ float sh[128];
    int b = blockIdx.x, t = threadIdx.x;
    float v = (t < CTX) ? runV[b*CTX + t] : -INFINITY;
    sh[t] = v; __syncthreads();
    for (int s2 = 64; s2 > 0; s2 >>= 1) { if (t < s2) sh[t] = fmaxf(sh[t], sh[t+s2]); __syncthreads(); }
    float m = sh[0]; __syncthreads();
    float e = (t < CTX) ? expf(v - m) : 0.f;
    sh[t] = e; __syncthreads();
    for (int s2 = 64; s2 > 0; s2 >>= 1) { if (t < s2) sh[t] += sh[t+s2]; __syncthreads(); }
    float w = e / sh[0]; __syncthreads();
    if (t < CTX) wts[b*CTX + t] = w;
    float yv = (t < CTX) ? candy[runI[b*CTX + t]] : 0.f;
    sh[t] = w * yv; __syncthreads();
    for (int s2 = 64; s2 > 0; s2 >>= 1) { if (t < s2) sh[t] += sh[t+s2]; __syncthreads(); }
    if (t == 0) wy[b] = sh[0];
}

// ---------- K6: Hw[b] = sum_c w_c * relu((k_b - ki_c) @ W_T1 + b_T1) ----------
#define TBN 128
__global__ __launch_bounds__(256) void k_tmlp(
    const float* __restrict__ kq, const float* __restrict__ ki,
    const int* __restrict__ runI, const float* __restrict__ wts,
    const float* __restrict__ WT1, const float* __restrict__ bT1,
    float* __restrict__ Hw)
{
    __shared__ float Ds[CTX][68];
    __shared__ float Ws[64][TBN];
    __shared__ float kb[DDIM];
    __shared__ float wsh[CTX];
    __shared__ int   idx[CTX];
    int b = blockIdx.x, nt = blockIdx.y;
    int tid = threadIdx.x;
    int tr = tid >> 4, tc = tid & 15;
    if (tid < CTX) { idx[tid] = runI[b*CTX + tid]; wsh[tid] = wts[b*CTX + tid]; }
    kb[tid] = kq[(size_t)b*DDIM + tid];
    __syncthreads();
    float acc[6][8] = {};
    for (int kc = 0; kc < DDIM; kc += 64) {
        for (int t = 0; t < 24; ++t) {
            int e = tid + t*256; int c = e >> 6, kkc = e & 63;
            Ds[c][kkc] = kb[kc + kkc] - ki[(size_t)idx[c]*DDIM + kc + kkc];
        }
        for (int t = 0; t < 32; ++t) {
            int e = tid + t*256; int r = e >> 7, c2 = e & 127;
            Ws[r][c2] = WT1[(size_t)(kc + r)*DIDIM + nt*TBN + c2];
        }
        __syncthreads();
        for (int kk = 0; kk < 64; ++kk) {
            float bw[8];
            #pragma unroll
            for (int j2 = 0; j2 < 8; ++j2) bw[j2] = Ws[kk][tc + 16*j2];
            #pragma unroll
            for (int i = 0; i < 6; ++i) {
                float a = Ds[tr*6+i][kk];
                #pragma unroll
                for (int j2 = 0; j2 < 8; ++j2) acc[i][j2] += a * bw[j2];
            }
        }
        __syncthreads();
    }
    float pc[8] = {};
    #pragma unroll
    for (int i = 0; i < 6; ++i) {
        int c = tr*6+i;
        float w = wsh[c];
        #pragma unroll
        for (int j2 = 0; j2 < 8; ++j2) {
            float h = acc[i][j2] + bT1[nt*TBN + tc + 16*j2];
            pc[j2] += w * fmaxf(h, 0.f);
        }
    }
    float* red = &Ds[0][0];   // reuse: 16*16*8 = 2048 floats
    __syncthreads();
    #pragma unroll
    for (int j2 = 0; j2 < 8; ++j2) red[(tr*16 + tc)*8 + j2] = pc[j2];
    __syncthreads();
    for (int s2 = 8; s2 > 0; s2 >>= 1) {
        if (tr < s2)
            #pragma unroll
            for (int j2 = 0; j2 < 8; ++j2)
                red[(tr*16+tc)*8+j2] += red[((tr+s2)*16+tc)*8+j2];
        __syncthreads();
    }
    if (tr == 0)
        #pragma unroll
        for (int j2 = 0; j2 < 8; ++j2)
            Hw[(size_t)b*DIDIM + nt*TBN + tc + 16*j2] = red[tc*8 + j2];
}

// ---------- K7: V assembly + residual + LN + MLP + LN + head ----------
__global__ __launch_bounds__(256) void k_final(
    const float* __restrict__ xenc, const float* __restrict__ Hw,
    const float* __restrict__ wy,
    const float* __restrict__ WY, const float* __restrict__ bY,
    const float* __restrict__ WT2,
    const float* __restrict__ lpg, const float* __restrict__ lpb,
    const float* __restrict__ WP1, const float* __restrict__ bP1,
    const float* __restrict__ WP2, const float* __restrict__ bP2,
    const float* __restrict__ logg, const float* __restrict__ lob,
    const float* __restrict__ Wout, const float* __restrict__ bout,
    float* __restrict__ out)
{
    __shared__ float hs[DIDIM];
    __shared__ float xs[DDIM];
    __shared__ float red[256];
    int b = blockIdx.x, j = threadIdx.x;
    hs[j] = Hw[(size_t)b*DIDIM + j];
    hs[j+256] = Hw[(size_t)b*DIDIM + j + 256];
    __syncthreads();
    float v = wy[b] * WY[j] + bY[j];
    for (int d = 0; d < DIDIM; ++d) v += hs[d] * WT2[d*DDIM + j];
    float x = xenc[(size_t)b*DDIM + j] + v;
    // LN1
    red[j] = x; __syncthreads();
    for (int s2 = 128; s2 > 0; s2 >>= 1) { if (j < s2) red[j] += red[j+s2]; __syncthreads(); }
    float mean = red[0] * (1.f/DDIM); __syncthreads();
    float xc = x - mean;
    red[j] = xc*xc; __syncthreads();
    for (int s2 = 128; s2 > 0; s2 >>= 1) { if (j < s2) red[j] += red[j+s2]; __syncthreads(); }
    float rstd = 1.f / sqrtf(red[0]*(1.f/DDIM) + 1e-5f); __syncthreads();
    xs[j] = xc * rstd * lpg[j] + lpb[j];
    __syncthreads();
    // hidden
    float u0 = bP1[j], u1 = bP1[j+256];
    for (int d = 0; d < DDIM; ++d) {
        float hd = xs[d];
        u0 += hd * WP1[d*DIDIM + j];
        u1 += hd * WP1[d*DIDIM + j + 256];
    }
    __syncthreads();
    hs[j] = fmaxf(u0, 0.f); hs[j+256] = fmaxf(u1, 0.f);
    __syncthreads();
    float x2 = x + bP2[j];
    for (int d = 0; d < DIDIM; ++d) x2 += hs[d] * WP2[d*DDIM + j];
    // LN2
    red[j] = x2; __syncthreads();
    for (int s2 = 128; s2 > 0; s2 >>= 1) { if (j < s2) red[j] += red[j+s2]; __syncthreads(); }
    float mean2 = red[0] * (1.f/DDIM); __syncthreads();
    float xc2 = x2 - mean2;
    red[j] = xc2*xc2; __syncthreads();
    for (int s2 = 128; s2 > 0; s2 >>= 1) { if (j < s2) red[j] += red[j+s2]; __syncthreads(); }
    float rstd2 = 1.f / sqrtf(red[0]*(1.f/DDIM) + 1e-5f); __syncthreads();
    float r = fmaxf(xc2 * rstd2 * logg[j] + lob[j], 0.f);
    red[j] = r * Wout[j]; __syncthreads();
    for (int s2 = 128; s2 > 0; s2 >>= 1) { if (j < s2) red[j] += red[j+s2]; __syncthreads(); }
    if (j == 0) out[b] = red[0] + bout[0];
}

extern "C" void kernel_launch(void* const* d_in, const int* in_sizes, int n_in,
                              void* d_out, int out_size, void* d_ws, size_t ws_size,
                              hipStream_t stream)
{
    (void)in_sizes; (void)n_in; (void)out_size;
    const float* x_num = (const float*)d_in[0];
    const float* cand  = (const float*)d_in[1];
    const float* candy = (const float*)d_in[2];
    const float* Wlin  = (const float*)d_in[3];
    const float* blin  = (const float*)d_in[4];
    const float* WK    = (const float*)d_in[5];
    const float* bK    = (const float*)d_in[6];
    const float* WY    = (const float*)d_in[7];
    const float* bY    = (const float*)d_in[8];
    const float* WT1   = (const float*)d_in[9];
    const float* bT1   = (const float*)d_in[10];
    const float* WT2   = (const float*)d_in[11];
    const float* lpg   = (const float*)d_in[12];
    const float* lpb   = (const float*)d_in[13];
    const float* WP1   = (const float*)d_in[14];
    const float* bP1   = (const float*)d_in[15];
    const float* WP2   = (const float*)d_in[16];
    const float* bP2   = (const float*)d_in[17];
    const float* logg  = (const float*)d_in[18];
    const float* lob   = (const float*)d_in[19];
    const float* Wout  = (const float*)d_in[20];
    const float* bout  = (const float*)d_in[21];
    float* out = (float*)d_out;

    float* ws = (float*)d_ws;
    size_t o = 0;
    float* Wf     = ws + o; o += (size_t)FDIM*DDIM;     // 32768
    float* bf     = ws + o; o += DDIM;                  // 256
    float* xenc   = ws + o; o += (size_t)BQ*DDIM;       // 262144
    float* kq     = ws + o; o += (size_t)BQ*DDIM;       // 262144
    float* kp     = ws + o; o += (size_t)BQ*FDIM;       // 131072
    float* kinorm = ws + o; o += 100352;
    float* runV   = ws + o; o += (size_t)BQ*CTX;
    int*   runI   = (int*)(ws + o); o += (size_t)BQ*CTX;
    float* wts    = ws + o; o += (size_t)BQ*CTX;
    float* wy     = ws + o; o += BQ;
    float* Hw     = ws + o; o += (size_t)BQ*DIDIM;
    float* ki     = ws + o; o += (size_t)NTOT*DDIM;     // 25,600,000
    float* schunk = ws + o;

    size_t availf = (ws_size/4 > o) ? (ws_size/4 - o) : 0;
    size_t ncl = (availf / BQ) & ~(size_t)63;
    int NC = (ncl >= 100032) ? 100032 : (int)ncl;
    if (NC < 64) NC = 64;
    int nch = (NTOT + NC - 1) / NC;

    k_fuse<<<dim3(FDIM+1), dim3(256), 0, stream>>>(Wlin, blin, WK, bK, Wf, bf);
    k_query<<<dim3(BQ), dim3(256), 0, stream>>>(x_num, Wlin, blin, Wf, bf, xenc, kq);
    k_kp<<<dim3(BQ), dim3(128), 0, stream>>>(kq, Wf, kp);
    k_cand<<<dim3(NTOT/8), dim3(256), 0, stream>>>(cand, Wf, bf, ki, kinorm);

    for (int c = 0; c < nch; ++c) {
        int n0 = c * NC;
        dim3 g3(NC/64, BQ/64);
        k_dist<<<g3, dim3(256), 0, stream>>>(cand, kp, kinorm, schunk, n0, NC);
        k_select<<<dim3(BQ), dim3(256), 0, stream>>>(schunk, runV, runI, n0, NC, c == 0 ? 1 : 0);
    }

    k_weights<<<dim3(BQ), dim3(128), 0, stream>>>(runV, runI, candy, wts, wy);
    k_tmlp<<<dim3(BQ, DIDIM/TBN), dim3(256), 0, stream>>>(kq, ki, runI, wts, WT1, bT1, Hw);
    k_final<<<dim3(BQ), dim3(256), 0, stream>>>(xenc, Hw, wy, WY, bY, WT2,
                                                lpg, lpb, WP1, bP1, WP2, bP2,
                                                logg, lob, Wout, bout, out);
}

// Round 3
// 1111.796 us; speedup vs baseline: 2.2754x; 2.2754x over previous
//
#include <hip/hip_runtime.h>
#include <math.h>

#define BQ 1024
#define FDIM 128
#define DDIM 256
#define DIDIM 512
#define NTOT 100000
#define NP 100096            // padded to multiple of 128
#define CTX 96
#define CTX2 128             // stage-1 running top-K
#define TBN 128

typedef _Float16 f16x8 __attribute__((ext_vector_type(8)));
typedef _Float16 f16x4 __attribute__((ext_vector_type(4)));
typedef float f32x4 __attribute__((ext_vector_type(4)));

// ---------- K0: fused encoder weights: Wf = W_lin@W_K, bf = b_lin@W_K + b_K ----------
__global__ __launch_bounds__(256) void k_fuse(
    const float* __restrict__ Wlin, const float* __restrict__ blin,
    const float* __restrict__ WK, const float* __restrict__ bK,
    float* __restrict__ Wf, float* __restrict__ bf)
{
    int i = blockIdx.x, j = threadIdx.x;
    if (i < FDIM) {
        float acc = 0.f;
        for (int l = 0; l < DDIM; ++l) acc += Wlin[i*DDIM + l] * WK[l*DDIM + j];
        Wf[i*DDIM + j] = acc;
    } else {
        float acc = bK[j];
        for (int l = 0; l < DDIM; ++l) acc += blin[l] * WK[l*DDIM + j];
        bf[j] = acc;
    }
}

// ---------- K0b: WfT1 = Wf @ W_T1  [128 x 512] ----------
__global__ __launch_bounds__(256) void k_fuse2(
    const float* __restrict__ Wf, const float* __restrict__ WT1, float* __restrict__ WfT1)
{
    __shared__ float wr[DDIM];
    int i = blockIdx.x, j = threadIdx.x;
    wr[j] = Wf[i*DDIM + j];
    __syncthreads();
    float a0 = 0.f, a1 = 0.f;
    for (int l = 0; l < DDIM; ++l) {
        float w = wr[l];
        a0 += w * WT1[(size_t)l*DIDIM + j];
        a1 += w * WT1[(size_t)l*DIDIM + j + 256];
    }
    WfT1[(size_t)i*DIDIM + j] = a0;
    WfT1[(size_t)i*DIDIM + j + 256] = a1;
}

// ---------- K1: per query row: x_enc = x@W_lin + b_lin ; k = x@Wf + bf ----------
__global__ __launch_bounds__(256) void k_query(
    const float* __restrict__ x, const float* __restrict__ Wlin,
    const float* __restrict__ blin, const float* __restrict__ Wf,
    const float* __restrict__ bf,
    float* __restrict__ xenc, float* __restrict__ kq)
{
    __shared__ float xs[FDIM];
    int b = blockIdx.x, j = threadIdx.x;
    if (j < FDIM) xs[j] = x[(size_t)b*FDIM + j];
    __syncthreads();
    float a0 = blin[j], a1 = bf[j];
    for (int l = 0; l < FDIM; ++l) {
        float xv = xs[l];
        a0 += xv * Wlin[l*DDIM + j];
        a1 += xv * Wf[l*DDIM + j];
    }
    xenc[(size_t)b*DDIM + j] = a0;
    kq[(size_t)b*DDIM + j] = a1;
}

// ---------- K1b: kp[b] = Wf @ k[b]  (128-dim projected query) ----------
__global__ __launch_bounds__(128) void k_kp(
    const float* __restrict__ kq, const float* __restrict__ Wf, float* __restrict__ kp)
{
    __shared__ float ks[DDIM];
    int b = blockIdx.x, l = threadIdx.x;
    ks[l] = kq[(size_t)b*DDIM + l];
    ks[l+128] = kq[(size_t)b*DDIM + l + 128];
    __syncthreads();
    float a = 0.f;
    for (int d = 0; d < DDIM; ++d) a += Wf[l*DDIM + d] * ks[d];
    kp[(size_t)b*FDIM + l] = a;
}

// ---------- conversions to split-f16 (scale-balanced): ----------
// A (kp2):  [hi | lo*2^6 | hi*2^-6]     B (cand2): [hi | hi*2^-6 | lo*2^6]
__global__ __launch_bounds__(256) void k_cvt_kp(
    const float* __restrict__ kp, _Float16* __restrict__ kp2)
{
    int t = blockIdx.x*256 + threadIdx.x;
    int row = t >> 5;
    int c4 = (t & 31) * 4;
    float4 v = *(const float4*)(kp + (size_t)row*FDIM + c4);
    float vv[4] = {v.x, v.y, v.z, v.w};
    f16x4 h, hs, l;
    #pragma unroll
    for (int q = 0; q < 4; ++q) {
        _Float16 hq = (_Float16)vv[q];
        float hf = (float)hq;
        h[q]  = hq;
        hs[q] = (_Float16)(hf * 0.015625f);
        l[q]  = (_Float16)((vv[q] - hf) * 64.f);
    }
    size_t b = (size_t)row*384 + c4;
    *(f16x4*)(kp2 + b)       = h;
    *(f16x4*)(kp2 + b + 128) = l;
    *(f16x4*)(kp2 + b + 256) = hs;
}

__global__ __launch_bounds__(256) void k_cvt_cand(
    const float* __restrict__ cand, _Float16* __restrict__ c2)
{
    int t = blockIdx.x*256 + threadIdx.x;
    int row = t >> 5;
    int c4 = (t & 31) * 4;
    float4 v = {0.f, 0.f, 0.f, 0.f};
    if (row < NTOT) v = *(const float4*)(cand + (size_t)row*FDIM + c4);
    float vv[4] = {v.x, v.y, v.z, v.w};
    f16x4 h, hs, l;
    #pragma unroll
    for (int q = 0; q < 4; ++q) {
        _Float16 hq = (_Float16)vv[q];
        float hf = (float)hq;
        h[q]  = hq;
        hs[q] = (_Float16)(hf * 0.015625f);
        l[q]  = (_Float16)((vv[q] - hf) * 64.f);
    }
    size_t b = (size_t)row*384 + c4;
    *(f16x4*)(c2 + b)       = h;
    *(f16x4*)(c2 + b + 128) = hs;
    *(f16x4*)(c2 + b + 256) = l;
}

// ---------- K2: kinorm[n] = ||cand_n@Wf + bf||^2  (INF for pad rows) ----------
__global__ __launch_bounds__(256) void k_norm(
    const float* __restrict__ cand, const float* __restrict__ Wf,
    const float* __restrict__ bf, float* __restrict__ kinorm)
{
    __shared__ float cs[8][FDIM];
    __shared__ float part[4][8];
    int n0 = blockIdx.x * 8, tid = threadIdx.x;
    #pragma unroll
    for (int t = 0; t < 4; ++t) {
        int e = tid + t*256; int r = e >> 7, c = e & 127;
        int n = n0 + r;
        cs[r][c] = (n < NTOT) ? cand[(size_t)n*FDIM + c] : 0.f;
    }
    __syncthreads();
    float acc[8];
    #pragma unroll
    for (int r = 0; r < 8; ++r) acc[r] = bf[tid];
    for (int l = 0; l < FDIM; ++l) {
        float w = Wf[l*DDIM + tid];
        #pragma unroll
        for (int r = 0; r < 8; ++r) acc[r] += cs[r][l] * w;
    }
    int lane = tid & 63, wv = tid >> 6;
    #pragma unroll
    for (int r = 0; r < 8; ++r) {
        float v = acc[r]*acc[r];
        for (int off = 32; off; off >>= 1) v += __shfl_xor(v, off, 64);
        if (lane == 0) part[wv][r] = v;
    }
    __syncthreads();
    if (tid < 8) {
        int n = n0 + tid;
        kinorm[n] = (n < NTOT) ? (part[0][tid] + part[1][tid] + part[2][tid] + part[3][tid])
                               : INFINITY;
    }
}

// ---------- K3: MFMA score GEMM:  s[m][nl] = kinorm[n] - 2 * (kp_m . cand_n) ----------
__global__ __launch_bounds__(256) void k_dist_mfma(
    const _Float16* __restrict__ kp2, const _Float16* __restrict__ cand2,
    const float* __restrict__ kinorm, float* __restrict__ s, int n0, int NC)
{
    __shared__ __align__(16) _Float16 As[128*64];
    __shared__ __align__(16) _Float16 Bs[128*64];
    int tid = threadIdx.x;
    int lane = tid & 63, wv = tid >> 6;
    int wm = wv >> 1, wn = wv & 1;          // 2x2 wave grid, 64x64 per wave
    int bm = blockIdx.x * 128;
    int bnl = blockIdx.y * 128;             // local n within chunk
    f32x4 acc[4][4] = {};
    const size_t baseA = (size_t)bm * 384;
    const size_t baseB = (size_t)(n0 + bnl) * 384;
    for (int kt = 0; kt < 6; ++kt) {
        #pragma unroll
        for (int r = 0; r < 4; ++r) {
            int e = (wv*4 + r)*64 + lane;
            const _Float16* ga = kp2  + baseA + (size_t)(e>>3)*384 + kt*64 + (e&7)*8;
            const _Float16* gb = cand2 + baseB + (size_t)(e>>3)*384 + kt*64 + (e&7)*8;
            __builtin_amdgcn_global_load_lds(
                (const __attribute__((address_space(1))) void*)ga,
                (__attribute__((address_space(3))) void*)(As + (wv*4 + r)*512), 16, 0, 0);
            __builtin_amdgcn_global_load_lds(
                (const __attribute__((address_space(1))) void*)gb,
                (__attribute__((address_space(3))) void*)(Bs + (wv*4 + r)*512), 16, 0, 0);
        }
        __syncthreads();
        #pragma unroll
        for (int kk = 0; kk < 2; ++kk) {
            f16x8 af[4], bfr[4];
            #pragma unroll
            for (int i = 0; i < 4; ++i)
                af[i] = *(const f16x8*)&As[(wm*64 + i*16 + (lane&15))*64 + kk*32 + (lane>>4)*8];
            #pragma unroll
            for (int j = 0; j < 4; ++j)
                bfr[j] = *(const f16x8*)&Bs[(wn*64 + j*16 + (lane&15))*64 + kk*32 + (lane>>4)*8];
            #pragma unroll
            for (int i = 0; i < 4; ++i)
                #pragma unroll
                for (int j = 0; j < 4; ++j)
                    acc[i][j] = __builtin_amdgcn_mfma_f32_16x16x32_f16(af[i], bfr[j], acc[i][j], 0, 0, 0);
        }
        __syncthreads();
    }
    #pragma unroll
    for (int i = 0; i < 4; ++i) {
        int m = bm + wm*64 + i*16 + (lane>>4)*4;
        #pragma unroll
        for (int j = 0; j < 4; ++j) {
            int nl = bnl + wn*64 + j*16 + (lane&15);
            float kn = kinorm[n0 + nl];
            #pragma unroll
            for (int rg = 0; rg < 4; ++rg)
                s[(size_t)(m + rg)*NC + nl] = kn - 2.f*acc[i][j][rg];
        }
    }
}

// ---------- K4: streaming top-128 (smallest) merge per row ----------
__device__ __forceinline__ void topk_merge(float* sv, int* si, int cntv, int tid)
{
    int nvalid = CTX2 + cntv;
    int size = 128;
    while (size < nvalid) size <<= 1;
    for (int i = nvalid + tid; i < size; i += 256) { sv[i] = INFINITY; si[i] = 0x7fffffff; }
    __syncthreads();
    for (int k2 = 2; k2 <= size; k2 <<= 1) {
        for (int jj = k2 >> 1; jj > 0; jj >>= 1) {
            for (int i = tid; i < size; i += 256) {
                int ix = i ^ jj;
                if (ix > i) {
                    bool up = ((i & k2) == 0);
                    float a = sv[i], b2 = sv[ix];
                    int ia = si[i], ib = si[ix];
                    bool gt = (a > b2) || (a == b2 && ia > ib);
                    if (gt == up) {
                        sv[i] = b2; sv[ix] = a;
                        si[i] = ib; si[ix] = ia;
                    }
                }
            }
            __syncthreads();
        }
    }
}

__global__ __launch_bounds__(256) void k_select(
    const float* __restrict__ s, float* __restrict__ runV, int* __restrict__ runI,
    int n0, int CC, int NC, int init)
{
    __shared__ float sv[4096];
    __shared__ int   si[4096];
    __shared__ float thresh;
    __shared__ int cnt;
    int b = blockIdx.x, tid = threadIdx.x;
    if (init) {
        for (int i = tid; i < CTX2; i += 256) { sv[i] = INFINITY; si[i] = 0x7fffffff; }
    } else {
        for (int i = tid; i < CTX2; i += 256) { sv[i] = runV[b*CTX2 + i]; si[i] = runI[b*CTX2 + i]; }
    }
    if (tid == 0) { cnt = 0; }
    __syncthreads();
    if (tid == 0) thresh = sv[CTX2-1];
    __syncthreads();
    const float* row = s + (size_t)b * NC;
    for (int base = 0; base < CC; base += 1024) {
        int j = base + tid*4;
        if (j < CC) {
            float4 v4 = *reinterpret_cast<const float4*>(row + j);
            float th = thresh;
            float vv[4] = {v4.x, v4.y, v4.z, v4.w};
            #pragma unroll
            for (int q = 0; q < 4; ++q) {
                if (vv[q] < th) {
                    int p = atomicAdd(&cnt, 1);
                    sv[CTX2 + p] = vv[q]; si[CTX2 + p] = n0 + j + q;
                }
            }
        }
        __syncthreads();
        int cv = cnt;
        if (cv > 1024) {
            topk_merge(sv, si, cv, tid);
            if (tid == 0) { thresh = sv[CTX2-1]; cnt = 0; }
            __syncthreads();
        }
    }
    __syncthreads();
    int cv = cnt;
    if (cv > 0) topk_merge(sv, si, cv, tid);
    __syncthreads();
    for (int i = tid; i < CTX2; i += 256) { runV[b*CTX2 + i] = sv[i]; runI[b*CTX2 + i] = si[i]; }
}

// ---------- K4b: exact fp32 rescore of the 128 survivors, emit final sorted top-96 ----------
__global__ __launch_bounds__(256) void k_rescore(
    const float* __restrict__ kp, const float* __restrict__ cand,
    const float* __restrict__ kinorm, const int* __restrict__ runI,
    float* __restrict__ finV, int* __restrict__ finI)
{
    __shared__ float kps[FDIM];
    __shared__ float sval[CTX2];
    __shared__ int   sidx[CTX2];
    int b = blockIdx.x, tid = threadIdx.x;
    int lane = tid & 63, wv = tid >> 6;
    if (tid < FDIM) kps[tid] = kp[(size_t)b*FDIM + tid];
    if (tid < CTX2) sidx[tid] = runI[b*CTX2 + tid];
    __syncthreads();
    for (int it = 0; it < 32; ++it) {
        int c = wv*32 + it;
        int n = sidx[c];
        const float2 v = *(const float2*)(cand + (size_t)n*FDIM + lane*2);
        float p = v.x*kps[lane*2] + v.y*kps[lane*2+1];
        for (int off = 32; off; off >>= 1) p += __shfl_xor(p, off, 64);
        if (lane == 0) sval[c] = kinorm[n] - 2.f*p;
    }
    __syncthreads();
    // full bitonic sort of 128 (ascending, index tie-break)
    for (int k2 = 2; k2 <= CTX2; k2 <<= 1) {
        for (int jj = k2 >> 1; jj > 0; jj >>= 1) {
            int i = tid;
            if (i < CTX2) {
                int ix = i ^ jj;
                if (ix > i) {
                    bool up = ((i & k2) == 0);
                    float a = sval[i], b2 = sval[ix];
                    int ia = sidx[i], ib = sidx[ix];
                    bool gt = (a > b2) || (a == b2 && ia > ib);
                    if (gt == up) {
                        sval[i] = b2; sval[ix] = a;
                        sidx[i] = ib; sidx[ix] = ia;
                    }
                }
            }
            __syncthreads();
        }
    }
    if (tid < CTX) { finV[b*CTX + tid] = sval[tid]; finI[b*CTX + tid] = sidx[tid]; }
}

// ---------- K5: softmax weights over selected scores + weighted y ----------
__global__ __launch_bounds__(128) void k_weights(
    const float* __restrict__ finV, const int* __restrict__ finI,
    const float* __restrict__ candy, float* __restrict__ wts, float* __restrict__ wy)
{
    __shared__ float sh[128];
    int b = blockIdx.x, t = threadIdx.x;
    float v = (t < CTX) ? finV[b*CTX + t] : -INFINITY;
    sh[t] = v; __syncthreads();
    for (int s2 = 64; s2 > 0; s2 >>= 1) { if (t < s2) sh[t] = fmaxf(sh[t], sh[t+s2]); __syncthreads(); }
    float m = sh[0]; __syncthreads();
    float e = (t < CTX) ? expf(v - m) : 0.f;
    sh[t] = e; __syncthreads();
    for (int s2 = 64; s2 > 0; s2 >>= 1) { if (t < s2) sh[t] += sh[t+s2]; __syncthreads(); }
    float w = e / sh[0]; __syncthreads();
    if (t < CTX) wts[b*CTX + t] = w;
    float yv = (t < CTX) ? candy[finI[b*CTX + t]] : 0.f;
    sh[t] = w * yv; __syncthreads();
    for (int s2 = 64; s2 > 0; s2 >>= 1) { if (t < s2) sh[t] += sh[t+s2]; __syncthreads(); }
    if (t == 0) wy[b] = sh[0];
}

// ---------- K6: Hw[b] = sum_c w_c * relu((x_b - cand_c) @ WfT1 + b_T1) ----------
__global__ __launch_bounds__(256) void k_tmlp(
    const float* __restrict__ x_num, const float* __restrict__ cand,
    const int* __restrict__ finI, const float* __restrict__ wts,
    const float* __restrict__ WfT1, const float* __restrict__ bT1,
    float* __restrict__ Hw)
{
    __shared__ float Ds[CTX][68];
    __shared__ float Ws[64][TBN];
    __shared__ float xb[FDIM];
    __shared__ float wsh[CTX];
    __shared__ int   idx[CTX];
    int b = blockIdx.x, nt = blockIdx.y;
    int tid = threadIdx.x;
    int tr = tid >> 4, tc = tid & 15;
    if (tid < CTX) { idx[tid] = finI[b*CTX + tid]; wsh[tid] = wts[b*CTX + tid]; }
    if (tid < FDIM) xb[tid] = x_num[(size_t)b*FDIM + tid];
    __syncthreads();
    float acc[6][8] = {};
    for (int kc = 0; kc < FDIM; kc += 64) {
        for (int t = 0; t < 24; ++t) {
            int e = tid + t*256; int c = e >> 6, kkc = e & 63;
            Ds[c][kkc] = xb[kc + kkc] - cand[(size_t)idx[c]*FDIM + kc + kkc];
        }
        for (int t = 0; t < 32; ++t) {
            int e = tid + t*256; int r = e >> 7, cc = e & 127;
            Ws[r][cc] = WfT1[(size_t)(kc + r)*DIDIM + nt*TBN + cc];
        }
        __syncthreads();
        for (int kk = 0; kk < 64; ++kk) {
            float bw[8];
            #pragma unroll
            for (int j2 = 0; j2 < 8; ++j2) bw[j2] = Ws[kk][tc + 16*j2];
            #pragma unroll
            for (int i = 0; i < 6; ++i) {
                float a = Ds[tr*6+i][kk];
                #pragma unroll
                for (int j2 = 0; j2 < 8; ++j2) acc[i][j2] += a * bw[j2];
            }
        }
        __syncthreads();
    }
    float pc[8] = {};
    #pragma unroll
    for (int i = 0; i < 6; ++i) {
        int c = tr*6+i;
        float w = wsh[c];
        #pragma unroll
        for (int j2 = 0; j2 < 8; ++j2) {
            float h = acc[i][j2] + bT1[nt*TBN + tc + 16*j2];
            pc[j2] += w * fmaxf(h, 0.f);
        }
    }
    float* red = &Ds[0][0];
    __syncthreads();
    #pragma unroll
    for (int j2 = 0; j2 < 8; ++j2) red[(tr*16 + tc)*8 + j2] = pc[j2];
    __syncthreads();
    for (int s2 = 8; s2 > 0; s2 >>= 1) {
        if (tr < s2)
            #pragma unroll
            for (int j2 = 0; j2 < 8; ++j2)
                red[(tr*16+tc)*8+j2] += red[((tr+s2)*16+tc)*8+j2];
        __syncthreads();
    }
    if (tr == 0)
        #pragma unroll
        for (int j2 = 0; j2 < 8; ++j2)
            Hw[(size_t)b*DIDIM + nt*TBN + tc + 16*j2] = red[tc*8 + j2];
}

// ---------- K7: V assembly + residual + LN + MLP + LN + head ----------
__global__ __launch_bounds__(256) void k_final(
    const float* __restrict__ xenc, const float* __restrict__ Hw,
    const float* __restrict__ wy,
    const float* __restrict__ WY, const float* __restrict__ bY,
    const float* __restrict__ WT2,
    const float* __restrict__ lpg, const float* __restrict__ lpb,
    const float* __restrict__ WP1, const float* __restrict__ bP1,
    const float* __restrict__ WP2, const float* __restrict__ bP2,
    const float* __restrict__ logg, const float* __restrict__ lob,
    const float* __restrict__ Wout, const float* __restrict__ bout,
    float* __restrict__ out)
{
    __shared__ float hs[DIDIM];
    __shared__ float xs[DDIM];
    __shared__ float red[256];
    int b = blockIdx.x, j = threadIdx.x;
    hs[j] = Hw[(size_t)b*DIDIM + j];
    hs[j+256] = Hw[(size_t)b*DIDIM + j + 256];
    __syncthreads();
    float v = wy[b] * WY[j] + bY[j];
    for (int d = 0; d < DIDIM; ++d) v += hs[d] * WT2[d*DDIM + j];
    float x = xenc[(size_t)b*DDIM + j] + v;
    red[j] = x; __syncthreads();
    for (int s2 = 128; s2 > 0; s2 >>= 1) { if (j < s2) red[j] += red[j+s2]; __syncthreads(); }
    float mean = red[0] * (1.f/DDIM); __syncthreads();
    float xc = x - mean;
    red[j] = xc*xc; __syncthreads();
    for (int s2 = 128; s2 > 0; s2 >>= 1) { if (j < s2) red[j] += red[j+s2]; __syncthreads(); }
    float rstd = 1.f / sqrtf(red[0]*(1.f/DDIM) + 1e-5f); __syncthreads();
    xs[j] = xc * rstd * lpg[j] + lpb[j];
    __syncthreads();
    float u0 = bP1[j], u1 = bP1[j+256];
    for (int d = 0; d < DDIM; ++d) {
        float hd = xs[d];
        u0 += hd * WP1[d*DIDIM + j];
        u1 += hd * WP1[d*DIDIM + j + 256];
    }
    __syncthreads();
    hs[j] = fmaxf(u0, 0.f); hs[j+256] = fmaxf(u1, 0.f);
    __syncthreads();
    float x2 = x + bP2[j];
    for (int d = 0; d < DIDIM; ++d) x2 += hs[d] * WP2[d*DDIM + j];
    red[j] = x2; __syncthreads();
    for (int s2 = 128; s2 > 0; s2 >>= 1) { if (j < s2) red[j] += red[j+s2]; __syncthreads(); }
    float mean2 = red[0] * (1.f/DDIM); __syncthreads();
    float xc2 = x2 - mean2;
    red[j] = xc2*xc2; __syncthreads();
    for (int s2 = 128; s2 > 0; s2 >>= 1) { if (j < s2) red[j] += red[j+s2]; __syncthreads(); }
    float rstd2 = 1.f / sqrtf(red[0]*(1.f/DDIM) + 1e-5f); __syncthreads();
    float r = fmaxf(xc2 * rstd2 * logg[j] + lob[j], 0.f);
    red[j] = r * Wout[j]; __syncthreads();
    for (int s2 = 128; s2 > 0; s2 >>= 1) { if (j < s2) red[j] += red[j+s2]; __syncthreads(); }
    if (j == 0) out[b] = red[0] + bout[0];
}

extern "C" void kernel_launch(void* const* d_in, const int* in_sizes, int n_in,
                              void* d_out, int out_size, void* d_ws, size_t ws_size,
                              hipStream_t stream)
{
    (void)in_sizes; (void)n_in; (void)out_size;
    const float* x_num = (const float*)d_in[0];
    const float* cand  = (const float*)d_in[1];
    const float* candy = (const float*)d_in[2];
    const float* Wlin  = (const float*)d_in[3];
    const float* blin  = (const float*)d_in[4];
    const float* WK    = (const float*)d_in[5];
    const float* bK    = (const float*)d_in[6];
    const float* WY    = (const float*)d_in[7];
    const float* bY    = (const float*)d_in[8];
    const float* WT1   = (const float*)d_in[9];
    const float* bT1   = (const float*)d_in[10];
    const float* WT2   = (const float*)d_in[11];
    const float* lpg   = (const float*)d_in[12];
    const float* lpb   = (const float*)d_in[13];
    const float* WP1   = (const float*)d_in[14];
    const float* bP1   = (const float*)d_in[15];
    const float* WP2   = (const float*)d_in[16];
    const float* bP2   = (const float*)d_in[17];
    const float* logg  = (const float*)d_in[18];
    const float* lob   = (const float*)d_in[19];
    const float* Wout  = (const float*)d_in[20];
    const float* bout  = (const float*)d_in[21];
    float* out = (float*)d_out;

    float* ws = (float*)d_ws;
    size_t o = 0;
    float* Wf     = ws + o; o += (size_t)FDIM*DDIM;
    float* bf     = ws + o; o += DDIM;
    float* WfT1   = ws + o; o += (size_t)FDIM*DIDIM;
    float* xenc   = ws + o; o += (size_t)BQ*DDIM;
    float* kq     = ws + o; o += (size_t)BQ*DDIM;
    float* kp     = ws + o; o += (size_t)BQ*FDIM;
    float* kinorm = ws + o; o += NP;
    float* runV   = ws + o; o += (size_t)BQ*CTX2;
    int*   runI   = (int*)(ws + o); o += (size_t)BQ*CTX2;
    float* finV   = ws + o; o += (size_t)BQ*CTX;
    int*   finI   = (int*)(ws + o); o += (size_t)BQ*CTX;
    float* wts    = ws + o; o += (size_t)BQ*CTX;
    float* wy     = ws + o; o += BQ;
    float* Hw     = ws + o; o += (size_t)BQ*DIDIM;
    _Float16* kp2 = (_Float16*)(ws + o); o += (size_t)BQ*384/2;
    _Float16* c2  = (_Float16*)(ws + o); o += (size_t)NP*384/2;
    float* schunk = ws + o;

    size_t availf = (ws_size/4 > o) ? (ws_size/4 - o) : 0;
    size_t ncl = (availf / BQ) & ~(size_t)127;
    int NC = (ncl >= NP) ? NP : (int)ncl;
    if (NC < 128) NC = 128;

    k_fuse<<<dim3(FDIM+1), dim3(256), 0, stream>>>(Wlin, blin, WK, bK, Wf, bf);
    k_fuse2<<<dim3(FDIM), dim3(256), 0, stream>>>(Wf, WT1, WfT1);
    k_query<<<dim3(BQ), dim3(256), 0, stream>>>(x_num, Wlin, blin, Wf, bf, xenc, kq);
    k_kp<<<dim3(BQ), dim3(128), 0, stream>>>(kq, Wf, kp);
    k_cvt_kp<<<dim3(BQ*FDIM/4/256), dim3(256), 0, stream>>>(kp, kp2);
    k_cvt_cand<<<dim3(NP*FDIM/4/256), dim3(256), 0, stream>>>(cand, c2);
    k_norm<<<dim3(NP/8), dim3(256), 0, stream>>>(cand, Wf, bf, kinorm);

    int first = 1;
    for (int n0 = 0; n0 < NP; n0 += NC) {
        int CC = (NP - n0 < NC) ? (NP - n0) : NC;
        k_dist_mfma<<<dim3(BQ/128, CC/128), dim3(256), 0, stream>>>(kp2, c2, kinorm, schunk, n0, NC);
        k_select<<<dim3(BQ), dim3(256), 0, stream>>>(schunk, runV, runI, n0, CC, NC, first);
        first = 0;
    }

    k_rescore<<<dim3(BQ), dim3(256), 0, stream>>>(kp, cand, kinorm, runI, finV, finI);
    k_weights<<<dim3(BQ), dim3(128), 0, stream>>>(finV, finI, candy, wts, wy);
    k_tmlp<<<dim3(BQ, DIDIM/TBN), dim3(256), 0, stream>>>(x_num, cand, finI, wts, WfT1, bT1, Hw);
    k_final<<<dim3(BQ), dim3(256), 0, stream>>>(xenc, Hw, wy, WY, bY, WT2,
                                                lpg, lpb, WP1, bP1, WP2, bP2,
                                                logg, lob, Wout, bout, out);
}

// Round 4
// 867.506 us; speedup vs baseline: 2.9161x; 1.2816x over previous
//
#include <hip/hip_runtime.h>
#include <math.h>

#define BQ 1024
#define BH 512               // per-half query rows
#define FDIM 128
#define DDIM 256
#define DIDIM 512
#define NTOT 100000
#define NP 100096            // padded to multiple of 128
#define SEG (NP/4)           // 25024, histogram/compact segment
#define CTX 96
#define CAP 8192             // per-row candidate capacity
#define TBN 128

typedef _Float16 f16x8 __attribute__((ext_vector_type(8)));
typedef _Float16 f16x4 __attribute__((ext_vector_type(4)));
typedef float f32x4 __attribute__((ext_vector_type(4)));

// ---------- K0: fused encoder weights: Wf = W_lin@W_K, bf = b_lin@W_K + b_K ----------
__global__ __launch_bounds__(256) void k_fuse(
    const float* __restrict__ Wlin, const float* __restrict__ blin,
    const float* __restrict__ WK, const float* __restrict__ bK,
    float* __restrict__ Wf, float* __restrict__ bf)
{
    int i = blockIdx.x, j = threadIdx.x;
    if (i < FDIM) {
        float acc = 0.f;
        for (int l = 0; l < DDIM; ++l) acc += Wlin[i*DDIM + l] * WK[l*DDIM + j];
        Wf[i*DDIM + j] = acc;
    } else {
        float acc = bK[j];
        for (int l = 0; l < DDIM; ++l) acc += blin[l] * WK[l*DDIM + j];
        bf[j] = acc;
    }
}

// ---------- K0b: WfT1 = Wf @ W_T1  [128 x 512] ----------
__global__ __launch_bounds__(256) void k_fuse2(
    const float* __restrict__ Wf, const float* __restrict__ WT1, float* __restrict__ WfT1)
{
    __shared__ float wr[DDIM];
    int i = blockIdx.x, j = threadIdx.x;
    wr[j] = Wf[i*DDIM + j];
    __syncthreads();
    float a0 = 0.f, a1 = 0.f;
    for (int l = 0; l < DDIM; ++l) {
        float w = wr[l];
        a0 += w * WT1[(size_t)l*DIDIM + j];
        a1 += w * WT1[(size_t)l*DIDIM + j + 256];
    }
    WfT1[(size_t)i*DIDIM + j] = a0;
    WfT1[(size_t)i*DIDIM + j + 256] = a1;
}

// ---------- K1: per query row: x_enc = x@W_lin + b_lin ; k = x@Wf + bf ----------
__global__ __launch_bounds__(256) void k_query(
    const float* __restrict__ x, const float* __restrict__ Wlin,
    const float* __restrict__ blin, const float* __restrict__ Wf,
    const float* __restrict__ bf,
    float* __restrict__ xenc, float* __restrict__ kq)
{
    __shared__ float xs[FDIM];
    int b = blockIdx.x, j = threadIdx.x;
    if (j < FDIM) xs[j] = x[(size_t)b*FDIM + j];
    __syncthreads();
    float a0 = blin[j], a1 = bf[j];
    for (int l = 0; l < FDIM; ++l) {
        float xv = xs[l];
        a0 += xv * Wlin[l*DDIM + j];
        a1 += xv * Wf[l*DDIM + j];
    }
    xenc[(size_t)b*DDIM + j] = a0;
    kq[(size_t)b*DDIM + j] = a1;
}

// ---------- K1b: kp[b] = Wf @ k[b]  (128-dim projected query) ----------
__global__ __launch_bounds__(128) void k_kp(
    const float* __restrict__ kq, const float* __restrict__ Wf, float* __restrict__ kp)
{
    __shared__ float ks[DDIM];
    int b = blockIdx.x, l = threadIdx.x;
    ks[l] = kq[(size_t)b*DDIM + l];
    ks[l+128] = kq[(size_t)b*DDIM + l + 128];
    __syncthreads();
    float a = 0.f;
    for (int d = 0; d < DDIM; ++d) a += Wf[l*DDIM + d] * ks[d];
    kp[(size_t)b*FDIM + l] = a;
}

// ---------- conversions to split-f16 (scale-balanced): ----------
// A (kp2):  [hi | lo*2^6 | hi*2^-6]     B (cand2): [hi | hi*2^-6 | lo*2^6]
__global__ __launch_bounds__(256) void k_cvt_kp(
    const float* __restrict__ kp, _Float16* __restrict__ kp2)
{
    int t = blockIdx.x*256 + threadIdx.x;
    int row = t >> 5;
    int c4 = (t & 31) * 4;
    float4 v = *(const float4*)(kp + (size_t)row*FDIM + c4);
    float vv[4] = {v.x, v.y, v.z, v.w};
    f16x4 h, hs, l;
    #pragma unroll
    for (int q = 0; q < 4; ++q) {
        _Float16 hq = (_Float16)vv[q];
        float hf = (float)hq;
        h[q]  = hq;
        hs[q] = (_Float16)(hf * 0.015625f);
        l[q]  = (_Float16)((vv[q] - hf) * 64.f);
    }
    size_t b = (size_t)row*384 + c4;
    *(f16x4*)(kp2 + b)       = h;
    *(f16x4*)(kp2 + b + 128) = l;
    *(f16x4*)(kp2 + b + 256) = hs;
}

__global__ __launch_bounds__(256) void k_cvt_cand(
    const float* __restrict__ cand, _Float16* __restrict__ c2)
{
    int t = blockIdx.x*256 + threadIdx.x;
    int row = t >> 5;
    int c4 = (t & 31) * 4;
    float4 v = {0.f, 0.f, 0.f, 0.f};
    if (row < NTOT) v = *(const float4*)(cand + (size_t)row*FDIM + c4);
    float vv[4] = {v.x, v.y, v.z, v.w};
    f16x4 h, hs, l;
    #pragma unroll
    for (int q = 0; q < 4; ++q) {
        _Float16 hq = (_Float16)vv[q];
        float hf = (float)hq;
        h[q]  = hq;
        hs[q] = (_Float16)(hf * 0.015625f);
        l[q]  = (_Float16)((vv[q] - hf) * 64.f);
    }
    size_t b = (size_t)row*384 + c4;
    *(f16x4*)(c2 + b)       = h;
    *(f16x4*)(c2 + b + 128) = hs;
    *(f16x4*)(c2 + b + 256) = l;
}

// ---------- K2: kinorm[n] = ||cand_n@Wf + bf||^2  (INF for pad rows) ----------
__global__ __launch_bounds__(256) void k_norm(
    const float* __restrict__ cand, const float* __restrict__ Wf,
    const float* __restrict__ bf, float* __restrict__ kinorm)
{
    __shared__ float cs[8][FDIM];
    __shared__ float part[4][8];
    int n0 = blockIdx.x * 8, tid = threadIdx.x;
    #pragma unroll
    for (int t = 0; t < 4; ++t) {
        int e = tid + t*256; int r = e >> 7, c = e & 127;
        int n = n0 + r;
        cs[r][c] = (n < NTOT) ? cand[(size_t)n*FDIM + c] : 0.f;
    }
    __syncthreads();
    float acc[8];
    #pragma unroll
    for (int r = 0; r < 8; ++r) acc[r] = bf[tid];
    for (int l = 0; l < FDIM; ++l) {
        float w = Wf[l*DDIM + tid];
        #pragma unroll
        for (int r = 0; r < 8; ++r) acc[r] += cs[r][l] * w;
    }
    int lane = tid & 63, wv = tid >> 6;
    #pragma unroll
    for (int r = 0; r < 8; ++r) {
        float v = acc[r]*acc[r];
        for (int off = 32; off; off >>= 1) v += __shfl_xor(v, off, 64);
        if (lane == 0) part[wv][r] = v;
    }
    __syncthreads();
    if (tid < 8) {
        int n = n0 + tid;
        kinorm[n] = (n < NTOT) ? (part[0][tid] + part[1][tid] + part[2][tid] + part[3][tid])
                               : INFINITY;
    }
}

// ---------- K3: MFMA score GEMM, f16 keys out. Conflict-free LDS via pre-permuted source.
// LDS layout: 16B chunk slot s = ((wq*8 + ii*2 + kk)*64 + q*16 + rl)
//   holds matrix row (wq*64+ii*16+rl), k-chunk (kk*4+q) of the 64-col kt-tile.
__global__ __launch_bounds__(256) void k_dist_mfma(
    const _Float16* __restrict__ kp2, const _Float16* __restrict__ cand2,
    const float* __restrict__ kinorm, _Float16* __restrict__ sb)
{
    __shared__ __align__(16) _Float16 As[128*64];
    __shared__ __align__(16) _Float16 Bs[128*64];
    int tid = threadIdx.x;
    int lane = tid & 63, wv = tid >> 6;
    int wm = wv >> 1, wn = wv & 1;          // 2x2 wave grid, 64x64 per wave
    int bm = blockIdx.x * 128;
    int bn = blockIdx.y * 128;
    f32x4 acc[4][4] = {};
    const size_t baseA = (size_t)bm * 384;
    const size_t baseB = (size_t)bn * 384;
    for (int kt = 0; kt < 6; ++kt) {
        #pragma unroll
        for (int r = 0; r < 4; ++r) {
            int w = wv*4 + r;
            int s = w*64 + lane;
            int rl = s & 15;
            int q  = (s >> 4) & 3;
            int kk2= (s >> 6) & 1;
            int ii = (s >> 7) & 3;
            int wq = (s >> 9) & 1;
            size_t goff = (size_t)(wq*64 + ii*16 + rl)*384 + kt*64 + (kk2*4 + q)*8;
            __builtin_amdgcn_global_load_lds(
                (const __attribute__((address_space(1))) void*)(kp2 + baseA + goff),
                (__attribute__((address_space(3))) void*)(As + w*512), 16, 0, 0);
            __builtin_amdgcn_global_load_lds(
                (const __attribute__((address_space(1))) void*)(cand2 + baseB + goff),
                (__attribute__((address_space(3))) void*)(Bs + w*512), 16, 0, 0);
        }
        __syncthreads();
        #pragma unroll
        for (int kk = 0; kk < 2; ++kk) {
            f16x8 af[4], bfr[4];
            #pragma unroll
            for (int i = 0; i < 4; ++i)
                af[i] = *(const f16x8*)&As[((wm*8 + i*2 + kk)*64 + (lane>>4)*16 + (lane&15))*8];
            #pragma unroll
            for (int j = 0; j < 4; ++j)
                bfr[j] = *(const f16x8*)&Bs[((wn*8 + j*2 + kk)*64 + (lane>>4)*16 + (lane&15))*8];
            #pragma unroll
            for (int i = 0; i < 4; ++i)
                #pragma unroll
                for (int j = 0; j < 4; ++j)
                    acc[i][j] = __builtin_amdgcn_mfma_f32_16x16x32_f16(af[i], bfr[j], acc[i][j], 0, 0, 0);
        }
        __syncthreads();
    }
    #pragma unroll
    for (int i = 0; i < 4; ++i) {
        int m = bm + wm*64 + i*16 + (lane>>4)*4;
        #pragma unroll
        for (int j = 0; j < 4; ++j) {
            int nl = bn + wn*64 + j*16 + (lane&15);
            float kn = kinorm[nl];
            #pragma unroll
            for (int rg = 0; rg < 4; ++rg)
                sb[(size_t)(m + rg)*NP + nl] = (_Float16)fmaxf(kn - 2.f*acc[i][j][rg], 0.f);
        }
    }
}

// ---------- K4a: zero histograms + counters ----------
__global__ __launch_bounds__(256) void k_zero(unsigned* __restrict__ hist, int* __restrict__ cnt)
{
    int b = blockIdx.x, t = threadIdx.x;
    #pragma unroll
    for (int i = 0; i < 4; ++i) hist[(size_t)b*1024 + t + i*256] = 0;
    if (t == 0) cnt[b] = 0;
}

// ---------- K4b: per-row 1024-bin histogram of f16 keys (u16 monotone) ----------
__global__ __launch_bounds__(256) void k_hist(
    const unsigned short* __restrict__ sb, unsigned* __restrict__ hist)
{
    __shared__ unsigned hloc[2][1024];
    int b = blockIdx.x, seg = blockIdx.y, tid = threadIdx.x;
    #pragma unroll
    for (int i = 0; i < 4; ++i) { hloc[0][tid + i*256] = 0; hloc[1][tid + i*256] = 0; }
    __syncthreads();
    const unsigned short* row = sb + (size_t)b*NP + (size_t)seg*SEG;
    unsigned* hs = hloc[tid & 1];
    for (int base = 0; base < SEG; base += 2048) {
        int j = base + tid*8;
        if (j < SEG) {
            uint4 u = *(const uint4*)(row + j);
            atomicAdd(&hs[(u.x & 0xffffu) >> 6], 1u);
            atomicAdd(&hs[(u.x >> 16) >> 6], 1u);
            atomicAdd(&hs[(u.y & 0xffffu) >> 6], 1u);
            atomicAdd(&hs[(u.y >> 16) >> 6], 1u);
            atomicAdd(&hs[(u.z & 0xffffu) >> 6], 1u);
            atomicAdd(&hs[(u.z >> 16) >> 6], 1u);
            atomicAdd(&hs[(u.w & 0xffffu) >> 6], 1u);
            atomicAdd(&hs[(u.w >> 16) >> 6], 1u);
        }
    }
    __syncthreads();
    #pragma unroll
    for (int i = 0; i < 4; ++i) {
        int bin = tid + i*256;
        unsigned v = hloc[0][bin] + hloc[1][bin];
        if (v) atomicAdd(&hist[(size_t)b*1024 + bin], v);
    }
}

// ---------- K4c: prefix-scan histogram, pick threshold bits (cum >= 96) ----------
__global__ __launch_bounds__(256) void k_hscan(
    const unsigned* __restrict__ hist, int* __restrict__ Tb)
{
    __shared__ unsigned p[256];
    __shared__ int tstar;
    int b = blockIdx.x, tid = threadIdx.x;
    const unsigned* h = hist + (size_t)b*1024;
    unsigned s0 = h[tid*4], s1 = h[tid*4+1], s2 = h[tid*4+2], s3 = h[tid*4+3];
    unsigned tot = s0 + s1 + s2 + s3;
    p[tid] = tot;
    if (tid == 0) tstar = 1023;
    __syncthreads();
    for (int off = 1; off < 256; off <<= 1) {
        unsigned t2 = (tid >= off) ? p[tid - off] : 0;
        __syncthreads();
        p[tid] += t2;
        __syncthreads();
    }
    unsigned c = p[tid] - tot;
    int found = -1;
    c += s0; if (c >= CTX) found = tid*4;
    if (found < 0) { c += s1; if (c >= CTX) found = tid*4+1; }
    if (found < 0) { c += s2; if (c >= CTX) found = tid*4+2; }
    if (found < 0) { c += s3; if (c >= CTX) found = tid*4+3; }
    if (found >= 0) atomicMin(&tstar, found);
    __syncthreads();
    if (tid == 0) Tb[b] = (tstar << 6) | 63;
}

// ---------- K4d: compact survivors (u16 key <= Tb) ----------
__global__ __launch_bounds__(256) void k_compact(
    const unsigned short* __restrict__ sb, const int* __restrict__ Tb,
    int* __restrict__ cnt, int* __restrict__ candI)
{
    int b = blockIdx.x, seg = blockIdx.y, tid = threadIdx.x;
    unsigned tb = (unsigned)Tb[b];
    const unsigned short* row = sb + (size_t)b*NP + (size_t)seg*SEG;
    int nbase = seg*SEG;
    for (int base = 0; base < SEG; base += 2048) {
        int j = base + tid*8;
        if (j < SEG) {
            uint4 u = *(const uint4*)(row + j);
            unsigned e[8] = { u.x & 0xffffu, u.x >> 16, u.y & 0xffffu, u.y >> 16,
                              u.z & 0xffffu, u.z >> 16, u.w & 0xffffu, u.w >> 16 };
            #pragma unroll
            for (int q = 0; q < 8; ++q) {
                if (e[q] <= tb) {
                    int p2 = atomicAdd(&cnt[b], 1);
                    if (p2 < CAP) candI[(size_t)b*CAP + p2] = nbase + j + q;
                }
            }
        }
    }
}

// ---------- K4e: exact fp32 rescore of survivors + bitonic top-96 ----------
__global__ __launch_bounds__(256) void k_resc(
    const float* __restrict__ kp, const float* __restrict__ cand,
    const float* __restrict__ kinorm, const int* __restrict__ cnt,
    const int* __restrict__ candI,
    float* __restrict__ finV, int* __restrict__ finI)
{
    __shared__ float kps[FDIM];
    __shared__ float sval[2048];
    __shared__ int   sidx[2048];
    int b = blockIdx.x, tid = threadIdx.x, lane = tid & 63, wv = tid >> 6;
    if (tid < FDIM) kps[tid] = kp[(size_t)b*FDIM + tid];
    if (tid < 128) { sval[tid] = INFINITY; sidx[tid] = 0x7fffffff; }
    int nc = cnt[b]; if (nc > CAP) nc = CAP;
    __syncthreads();
    for (int c0 = 0; c0 < nc; c0 += 1920) {
        int m = nc - c0; if (m > 1920) m = 1920;
        for (int c = wv; c < m; c += 4) {
            int n = candI[(size_t)b*CAP + c0 + c];
            float2 v = *(const float2*)(cand + (size_t)n*FDIM + lane*2);
            float p = v.x*kps[lane*2] + v.y*kps[lane*2+1];
            for (int off = 32; off; off >>= 1) p += __shfl_xor(p, off, 64);
            if (lane == 0) { sval[128 + c] = kinorm[n] - 2.f*p; sidx[128 + c] = n; }
        }
        __syncthreads();
        int nv = 128 + m;
        int size = 256; while (size < nv) size <<= 1;
        for (int i2 = nv + tid; i2 < size; i2 += 256) { sval[i2] = INFINITY; sidx[i2] = 0x7fffffff; }
        __syncthreads();
        for (int k2 = 2; k2 <= size; k2 <<= 1) {
            for (int jj = k2 >> 1; jj > 0; jj >>= 1) {
                for (int i = tid; i < size; i += 256) {
                    int ix = i ^ jj;
                    if (ix > i) {
                        bool up = ((i & k2) == 0);
                        float a = sval[i], b2 = sval[ix];
                        int ia = sidx[i], ib = sidx[ix];
                        bool gt = (a > b2) || (a == b2 && ia > ib);
                        if (gt == up) {
                            sval[i] = b2; sval[ix] = a;
                            sidx[i] = ib; sidx[ix] = ia;
                        }
                    }
                }
                __syncthreads();
            }
        }
    }
    if (tid < CTX) { finV[(size_t)b*CTX + tid] = sval[tid]; finI[(size_t)b*CTX + tid] = sidx[tid]; }
}

// ---------- K5: softmax weights over selected scores + weighted y ----------
__global__ __launch_bounds__(128) void k_weights(
    const float* __restrict__ finV, const int* __restrict__ finI,
    const float* __restrict__ candy, float* __restrict__ wts, float* __restrict__ wy)
{
    __shared__ float sh[128];
    int b = blockIdx.x, t = threadIdx.x;
    float v = (t < CTX) ? finV[b*CTX + t] : -INFINITY;
    sh[t] = v; __syncthreads();
    for (int s2 = 64; s2 > 0; s2 >>= 1) { if (t < s2) sh[t] = fmaxf(sh[t], sh[t+s2]); __syncthreads(); }
    float m = sh[0]; __syncthreads();
    float e = (t < CTX) ? expf(v - m) : 0.f;
    sh[t] = e; __syncthreads();
    for (int s2 = 64; s2 > 0; s2 >>= 1) { if (t < s2) sh[t] += sh[t+s2]; __syncthreads(); }
    float w = e / sh[0]; __syncthreads();
    if (t < CTX) wts[b*CTX + t] = w;
    float yv = (t < CTX) ? candy[finI[b*CTX + t]] : 0.f;
    sh[t] = w * yv; __syncthreads();
    for (int s2 = 64; s2 > 0; s2 >>= 1) { if (t < s2) sh[t] += sh[t+s2]; __syncthreads(); }
    if (t == 0) wy[b] = sh[0];
}

// ---------- K6: Hw[b] = sum_c w_c * relu((x_b - cand_c) @ WfT1 + b_T1) ----------
__global__ __launch_bounds__(256) void k_tmlp(
    const float* __restrict__ x_num, const float* __restrict__ cand,
    const int* __restrict__ finI, const float* __restrict__ wts,
    const float* __restrict__ WfT1, const float* __restrict__ bT1,
    float* __restrict__ Hw)
{
    __shared__ float Ds[CTX][68];
    __shared__ float Ws[64][TBN];
    __shared__ float xb[FDIM];
    __shared__ float wsh[CTX];
    __shared__ int   idx[CTX];
    int b = blockIdx.x, nt = blockIdx.y;
    int tid = threadIdx.x;
    int tr = tid >> 4, tc = tid & 15;
    if (tid < CTX) { idx[tid] = finI[b*CTX + tid]; wsh[tid] = wts[b*CTX + tid]; }
    if (tid < FDIM) xb[tid] = x_num[(size_t)b*FDIM + tid];
    __syncthreads();
    float acc[6][8] = {};
    for (int kc = 0; kc < FDIM; kc += 64) {
        for (int t = 0; t < 24; ++t) {
            int e = tid + t*256; int c = e >> 6, kkc = e & 63;
            Ds[c][kkc] = xb[kc + kkc] - cand[(size_t)idx[c]*FDIM + kc + kkc];
        }
        for (int t = 0; t < 32; ++t) {
            int e = tid + t*256; int r = e >> 7, cc = e & 127;
            Ws[r][cc] = WfT1[(size_t)(kc + r)*DIDIM + nt*TBN + cc];
        }
        __syncthreads();
        for (int kk = 0; kk < 64; ++kk) {
            float bw[8];
            #pragma unroll
            for (int j2 = 0; j2 < 8; ++j2) bw[j2] = Ws[kk][tc + 16*j2];
            #pragma unroll
            for (int i = 0; i < 6; ++i) {
                float a = Ds[tr*6+i][kk];
                #pragma unroll
                for (int j2 = 0; j2 < 8; ++j2) acc[i][j2] += a * bw[j2];
            }
        }
        __syncthreads();
    }
    float pc[8] = {};
    #pragma unroll
    for (int i = 0; i < 6; ++i) {
        int c = tr*6+i;
        float w = wsh[c];
        #pragma unroll
        for (int j2 = 0; j2 < 8; ++j2) {
            float h = acc[i][j2] + bT1[nt*TBN + tc + 16*j2];
            pc[j2] += w * fmaxf(h, 0.f);
        }
    }
    float* red = &Ds[0][0];
    __syncthreads();
    #pragma unroll
    for (int j2 = 0; j2 < 8; ++j2) red[(tr*16 + tc)*8 + j2] = pc[j2];
    __syncthreads();
    for (int s2 = 8; s2 > 0; s2 >>= 1) {
        if (tr < s2)
            #pragma unroll
            for (int j2 = 0; j2 < 8; ++j2)
                red[(tr*16+tc)*8+j2] += red[((tr+s2)*16+tc)*8+j2];
        __syncthreads();
    }
    if (tr == 0)
        #pragma unroll
        for (int j2 = 0; j2 < 8; ++j2)
            Hw[(size_t)b*DIDIM + nt*TBN + tc + 16*j2] = red[tc*8 + j2];
}

// ---------- K7: V assembly + residual + LN + MLP + LN + head ----------
__global__ __launch_bounds__(256) void k_final(
    const float* __restrict__ xenc, const float* __restrict__ Hw,
    const float* __restrict__ wy,
    const float* __restrict__ WY, const float* __restrict__ bY,
    const float* __restrict__ WT2,
    const float* __restrict__ lpg, const float* __restrict__ lpb,
    const float* __restrict__ WP1, const float* __restrict__ bP1,
    const float* __restrict__ WP2, const float* __restrict__ bP2,
    const float* __restrict__ logg, const float* __restrict__ lob,
    const float* __restrict__ Wout, const float* __restrict__ bout,
    float* __restrict__ out)
{
    __shared__ float hs[DIDIM];
    __shared__ float xs[DDIM];
    __shared__ float red[256];
    int b = blockIdx.x, j = threadIdx.x;
    hs[j] = Hw[(size_t)b*DIDIM + j];
    hs[j+256] = Hw[(size_t)b*DIDIM + j + 256];
    __syncthreads();
    float v = wy[b] * WY[j] + bY[j];
    for (int d = 0; d < DIDIM; ++d) v += hs[d] * WT2[d*DDIM + j];
    float x = xenc[(size_t)b*DDIM + j] + v;
    red[j] = x; __syncthreads();
    for (int s2 = 128; s2 > 0; s2 >>= 1) { if (j < s2) red[j] += red[j+s2]; __syncthreads(); }
    float mean = red[0] * (1.f/DDIM); __syncthreads();
    float xc = x - mean;
    red[j] = xc*xc; __syncthreads();
    for (int s2 = 128; s2 > 0; s2 >>= 1) { if (j < s2) red[j] += red[j+s2]; __syncthreads(); }
    float rstd = 1.f / sqrtf(red[0]*(1.f/DDIM) + 1e-5f); __syncthreads();
    xs[j] = xc * rstd * lpg[j] + lpb[j];
    __syncthreads();
    float u0 = bP1[j], u1 = bP1[j+256];
    for (int d = 0; d < DDIM; ++d) {
        float hd = xs[d];
        u0 += hd * WP1[d*DIDIM + j];
        u1 += hd * WP1[d*DIDIM + j + 256];
    }
    __syncthreads();
    hs[j] = fmaxf(u0, 0.f); hs[j+256] = fmaxf(u1, 0.f);
    __syncthreads();
    float x2 = x + bP2[j];
    for (int d = 0; d < DIDIM; ++d) x2 += hs[d] * WP2[d*DDIM + j];
    red[j] = x2; __syncthreads();
    for (int s2 = 128; s2 > 0; s2 >>= 1) { if (j < s2) red[j] += red[j+s2]; __syncthreads(); }
    float mean2 = red[0] * (1.f/DDIM); __syncthreads();
    float xc2 = x2 - mean2;
    red[j] = xc2*xc2; __syncthreads();
    for (int s2 = 128; s2 > 0; s2 >>= 1) { if (j < s2) red[j] += red[j+s2]; __syncthreads(); }
    float rstd2 = 1.f / sqrtf(red[0]*(1.f/DDIM) + 1e-5f); __syncthreads();
    float r = fmaxf(xc2 * rstd2 * logg[j] + lob[j], 0.f);
    red[j] = r * Wout[j]; __syncthreads();
    for (int s2 = 128; s2 > 0; s2 >>= 1) { if (j < s2) red[j] += red[j+s2]; __syncthreads(); }
    if (j == 0) out[b] = red[0] + bout[0];
}

extern "C" void kernel_launch(void* const* d_in, const int* in_sizes, int n_in,
                              void* d_out, int out_size, void* d_ws, size_t ws_size,
                              hipStream_t stream)
{
    (void)in_sizes; (void)n_in; (void)out_size; (void)ws_size;
    const float* x_num = (const float*)d_in[0];
    const float* cand  = (const float*)d_in[1];
    const float* candy = (const float*)d_in[2];
    const float* Wlin  = (const float*)d_in[3];
    const float* blin  = (const float*)d_in[4];
    const float* WK    = (const float*)d_in[5];
    const float* bK    = (const float*)d_in[6];
    const float* WY    = (const float*)d_in[7];
    const float* bY    = (const float*)d_in[8];
    const float* WT1   = (const float*)d_in[9];
    const float* bT1   = (const float*)d_in[10];
    const float* WT2   = (const float*)d_in[11];
    const float* lpg   = (const float*)d_in[12];
    const float* lpb   = (const float*)d_in[13];
    const float* WP1   = (const float*)d_in[14];
    const float* bP1   = (const float*)d_in[15];
    const float* WP2   = (const float*)d_in[16];
    const float* bP2   = (const float*)d_in[17];
    const float* logg  = (const float*)d_in[18];
    const float* lob   = (const float*)d_in[19];
    const float* Wout  = (const float*)d_in[20];
    const float* bout  = (const float*)d_in[21];
    float* out = (float*)d_out;

    float* ws = (float*)d_ws;
    size_t o = 0;
    float* Wf     = ws + o; o += (size_t)FDIM*DDIM;
    float* bf     = ws + o; o += DDIM;
    float* WfT1   = ws + o; o += (size_t)FDIM*DIDIM;
    float* xenc   = ws + o; o += (size_t)BQ*DDIM;
    float* kq     = ws + o; o += (size_t)BQ*DDIM;
    float* kp     = ws + o; o += (size_t)BQ*FDIM;
    float* kinorm = ws + o; o += NP;
    float* finV   = ws + o; o += (size_t)BQ*CTX;
    int*   finI   = (int*)(ws + o); o += (size_t)BQ*CTX;
    float* wts    = ws + o; o += (size_t)BQ*CTX;
    float* wy     = ws + o; o += BQ;
    float* Hw     = ws + o; o += (size_t)BQ*DIDIM;
    _Float16* kp2 = (_Float16*)(ws + o); o += (size_t)BQ*384/2;
    _Float16* c2  = (_Float16*)(ws + o); o += (size_t)NP*384/2;
    unsigned* hist= (unsigned*)(ws + o); o += (size_t)BH*1024;
    int*   cnt    = (int*)(ws + o); o += BH;
    int*   Tb     = (int*)(ws + o); o += BH;
    int*   candI  = (int*)(ws + o); o += (size_t)BH*CAP;
    _Float16* sb  = (_Float16*)(ws + o); o += (size_t)BH*NP/2;

    k_fuse<<<dim3(FDIM+1), dim3(256), 0, stream>>>(Wlin, blin, WK, bK, Wf, bf);
    k_fuse2<<<dim3(FDIM), dim3(256), 0, stream>>>(Wf, WT1, WfT1);
    k_query<<<dim3(BQ), dim3(256), 0, stream>>>(x_num, Wlin, blin, Wf, bf, xenc, kq);
    k_kp<<<dim3(BQ), dim3(128), 0, stream>>>(kq, Wf, kp);
    k_cvt_kp<<<dim3(BQ*FDIM/4/256), dim3(256), 0, stream>>>(kp, kp2);
    k_cvt_cand<<<dim3(NP*FDIM/4/256), dim3(256), 0, stream>>>(cand, c2);
    k_norm<<<dim3(NP/8), dim3(256), 0, stream>>>(cand, Wf, bf, kinorm);

    for (int bh = 0; bh < 2; ++bh) {
        const _Float16* kp2h = kp2 + (size_t)bh*BH*384;
        const float* kph = kp + (size_t)bh*BH*FDIM;
        float* finVh = finV + (size_t)bh*BH*CTX;
        int*   finIh = finI + (size_t)bh*BH*CTX;
        k_zero<<<dim3(BH), dim3(256), 0, stream>>>(hist, cnt);
        k_dist_mfma<<<dim3(BH/128, NP/128), dim3(256), 0, stream>>>(kp2h, c2, kinorm, sb);
        k_hist<<<dim3(BH, 4), dim3(256), 0, stream>>>((const unsigned short*)sb, hist);
        k_hscan<<<dim3(BH), dim3(256), 0, stream>>>(hist, Tb);
        k_compact<<<dim3(BH, 4), dim3(256), 0, stream>>>((const unsigned short*)sb, Tb, cnt, candI);
        k_resc<<<dim3(BH), dim3(256), 0, stream>>>(kph, cand, kinorm, cnt, candI, finVh, finIh);
    }

    k_weights<<<dim3(BQ), dim3(128), 0, stream>>>(finV, finI, candy, wts, wy);
    k_tmlp<<<dim3(BQ, DIDIM/TBN), dim3(256), 0, stream>>>(x_num, cand, finI, wts, WfT1, bT1, Hw);
    k_final<<<dim3(BQ), dim3(256), 0, stream>>>(xenc, Hw, wy, WY, bY, WT2,
                                                lpg, lpb, WP1, bP1, WP2, bP2,
                                                logg, lob, Wout, bout, out);
}

// Round 6
// 724.350 us; speedup vs baseline: 3.4925x; 1.1976x over previous
//
#include <hip/hip_runtime.h>
#include <math.h>

#define BQ 1024
#define BH 512               // per-half query rows
#define FDIM 128
#define DDIM 256
#define DIDIM 512
#define NTOT 100000
#define NP 100096            // padded to multiple of 128
#define SEG (NP/4)           // 25024, histogram/compact segment
#define CTX 96
#define CAP 8192             // per-row candidate capacity

typedef _Float16 f16x8 __attribute__((ext_vector_type(8)));
typedef _Float16 f16x4 __attribute__((ext_vector_type(4)));
typedef _Float16 f16x2 __attribute__((ext_vector_type(2)));
typedef float f32x4 __attribute__((ext_vector_type(4)));

// ---------- K0: fused encoder weights: Wf = W_lin@W_K, bf = b_lin@W_K + b_K; bf[256]=||bf||^2 ----------
__global__ __launch_bounds__(256) void k_fuse(
    const float* __restrict__ Wlin, const float* __restrict__ blin,
    const float* __restrict__ WK, const float* __restrict__ bK,
    float* __restrict__ Wf, float* __restrict__ bf)
{
    __shared__ float red[256];
    int i = blockIdx.x, j = threadIdx.x;
    if (i < FDIM) {
        float acc = 0.f;
        for (int l = 0; l < DDIM; ++l) acc += Wlin[i*DDIM + l] * WK[l*DDIM + j];
        Wf[i*DDIM + j] = acc;
    } else {
        float acc = bK[j];
        for (int l = 0; l < DDIM; ++l) acc += blin[l] * WK[l*DDIM + j];
        bf[j] = acc;
        red[j] = acc*acc; __syncthreads();
        for (int s2 = 128; s2 > 0; s2 >>= 1) { if (j < s2) red[j] += red[j+s2]; __syncthreads(); }
        if (j == 0) bf[256] = red[0];
    }
}

// ---------- K0b: WfT1 = Wf @ W_T1  [128 x 512] ----------
__global__ __launch_bounds__(256) void k_fuse2(
    const float* __restrict__ Wf, const float* __restrict__ WT1, float* __restrict__ WfT1)
{
    __shared__ float wr[DDIM];
    int i = blockIdx.x, j = threadIdx.x;
    wr[j] = Wf[i*DDIM + j];
    __syncthreads();
    float a0 = 0.f, a1 = 0.f;
    for (int l = 0; l < DDIM; ++l) {
        float w = wr[l];
        a0 += w * WT1[(size_t)l*DIDIM + j];
        a1 += w * WT1[(size_t)l*DIDIM + j + 256];
    }
    WfT1[(size_t)i*DIDIM + j] = a0;
    WfT1[(size_t)i*DIDIM + j + 256] = a1;
}

// ---------- K0c: split-f16 weight pack, A-ordering [hi | lo*64 | hi/64].
// rows 0..255: Wf columns; rows 256..767: WfT1 columns.
__global__ __launch_bounds__(128) void k_cvt_w(
    const float* __restrict__ Wf, const float* __restrict__ WfT1, _Float16* __restrict__ Wsp)
{
    int j = blockIdx.x, l = threadIdx.x;
    float w = (j < DDIM) ? Wf[l*DDIM + j] : WfT1[(size_t)l*DIDIM + (j - DDIM)];
    _Float16 h = (_Float16)w;
    float hf = (float)h;
    Wsp[(size_t)j*384 + l]       = h;
    Wsp[(size_t)j*384 + 128 + l] = (_Float16)((w - hf) * 64.f);
    Wsp[(size_t)j*384 + 256 + l] = (_Float16)(hf * 0.015625f);
}

// ---------- K1: per query row: x_enc = x@W_lin + b_lin ; k = x@Wf + bf ----------
__global__ __launch_bounds__(256) void k_query(
    const float* __restrict__ x, const float* __restrict__ Wlin,
    const float* __restrict__ blin, const float* __restrict__ Wf,
    const float* __restrict__ bf,
    float* __restrict__ xenc, float* __restrict__ kq)
{
    __shared__ float xs[FDIM];
    int b = blockIdx.x, j = threadIdx.x;
    if (j < FDIM) xs[j] = x[(size_t)b*FDIM + j];
    __syncthreads();
    float a0 = blin[j], a1 = bf[j];
    for (int l = 0; l < FDIM; ++l) {
        float xv = xs[l];
        a0 += xv * Wlin[l*DDIM + j];
        a1 += xv * Wf[l*DDIM + j];
    }
    xenc[(size_t)b*DDIM + j] = a0;
    kq[(size_t)b*DDIM + j] = a1;
}

// ---------- K1b: kp[b] = Wf @ k[b]  (128-dim projected query) ----------
__global__ __launch_bounds__(128) void k_kp(
    const float* __restrict__ kq, const float* __restrict__ Wf, float* __restrict__ kp)
{
    __shared__ float ks[DDIM];
    int b = blockIdx.x, l = threadIdx.x;
    ks[l] = kq[(size_t)b*DDIM + l];
    ks[l+128] = kq[(size_t)b*DDIM + l + 128];
    __syncthreads();
    float a = 0.f;
    for (int d = 0; d < DDIM; ++d) a += Wf[l*DDIM + d] * ks[d];
    kp[(size_t)b*FDIM + l] = a;
}

// ---------- K1c: xP[b] = x_num[b] @ WfT1 + bT1  [1024 x 512] ----------
__global__ __launch_bounds__(256) void k_xp(
    const float* __restrict__ x, const float* __restrict__ WfT1,
    const float* __restrict__ bT1, float* __restrict__ xP)
{
    __shared__ float xs[FDIM];
    int b = blockIdx.x, j = threadIdx.x;
    if (j < FDIM) xs[j] = x[(size_t)b*FDIM + j];
    __syncthreads();
    float a0 = bT1[j], a1 = bT1[j + 256];
    for (int l = 0; l < FDIM; ++l) {
        float xv = xs[l];
        a0 += xv * WfT1[(size_t)l*DIDIM + j];
        a1 += xv * WfT1[(size_t)l*DIDIM + j + 256];
    }
    xP[(size_t)b*DIDIM + j] = a0;
    xP[(size_t)b*DIDIM + j + 256] = a1;
}

// ---------- conversions to split-f16 (scale-balanced): ----------
// A (kp2):  [hi | lo*2^6 | hi*2^-6]     B (cand2): [hi | hi*2^-6 | lo*2^6]
__global__ __launch_bounds__(256) void k_cvt_kp(
    const float* __restrict__ kp, _Float16* __restrict__ kp2)
{
    int t = blockIdx.x*256 + threadIdx.x;
    int row = t >> 5;
    int c4 = (t & 31) * 4;
    float4 v = *(const float4*)(kp + (size_t)row*FDIM + c4);
    float vv[4] = {v.x, v.y, v.z, v.w};
    f16x4 h, hs, l;
    #pragma unroll
    for (int q = 0; q < 4; ++q) {
        _Float16 hq = (_Float16)vv[q];
        float hf = (float)hq;
        h[q]  = hq;
        hs[q] = (_Float16)(hf * 0.015625f);
        l[q]  = (_Float16)((vv[q] - hf) * 64.f);
    }
    size_t b = (size_t)row*384 + c4;
    *(f16x4*)(kp2 + b)       = h;
    *(f16x4*)(kp2 + b + 128) = l;
    *(f16x4*)(kp2 + b + 256) = hs;
}

__global__ __launch_bounds__(256) void k_cvt_cand(
    const float* __restrict__ cand, _Float16* __restrict__ c2)
{
    int t = blockIdx.x*256 + threadIdx.x;
    int row = t >> 5;
    int c4 = (t & 31) * 4;
    float4 v = {0.f, 0.f, 0.f, 0.f};
    if (row < NTOT) v = *(const float4*)(cand + (size_t)row*FDIM + c4);
    float vv[4] = {v.x, v.y, v.z, v.w};
    f16x4 h, hs, l;
    #pragma unroll
    for (int q = 0; q < 4; ++q) {
        _Float16 hq = (_Float16)vv[q];
        float hf = (float)hq;
        h[q]  = hq;
        hs[q] = (_Float16)(hf * 0.015625f);
        l[q]  = (_Float16)((vv[q] - hf) * 64.f);
    }
    size_t b = (size_t)row*384 + c4;
    *(f16x4*)(c2 + b)       = h;
    *(f16x4*)(c2 + b + 128) = hs;
    *(f16x4*)(c2 + b + 256) = l;
}

// ---------- Generic split-f16 MFMA GEMM: rows of A (c2) x rows of B (Wsp), K=384.
// MODE 0: store f16 P[m][col] (NCOL=512).  MODE 1: norm partials knp[slot][m].
template<int MODE>
__global__ __launch_bounds__(256) void k_csplit(
    const _Float16* __restrict__ A, const _Float16* __restrict__ B,
    _Float16* __restrict__ P, float* __restrict__ knp, const float* __restrict__ bf)
{
    __shared__ __align__(16) _Float16 As[128*64];
    __shared__ __align__(16) _Float16 Bs[128*64];
    int tid = threadIdx.x;
    int lane = tid & 63, wv = tid >> 6;
    int wm = wv >> 1, wn = wv & 1;
    int bm = blockIdx.x * 128;
    int bn = blockIdx.y * 128;
    f32x4 acc[4][4] = {};
    const size_t baseA = (size_t)bm * 384;
    const size_t baseB = (size_t)bn * 384;
    for (int kt = 0; kt < 6; ++kt) {
        #pragma unroll
        for (int r = 0; r < 4; ++r) {
            int w = wv*4 + r;
            int s = w*64 + lane;
            int rl = s & 15;
            int q  = (s >> 4) & 3;
            int kk2= (s >> 6) & 1;
            int ii = (s >> 7) & 3;
            int wq = (s >> 9) & 1;
            size_t goff = (size_t)(wq*64 + ii*16 + rl)*384 + kt*64 + (kk2*4 + q)*8;
            __builtin_amdgcn_global_load_lds(
                (const __attribute__((address_space(1))) void*)(A + baseA + goff),
                (__attribute__((address_space(3))) void*)(As + w*512), 16, 0, 0);
            __builtin_amdgcn_global_load_lds(
                (const __attribute__((address_space(1))) void*)(B + baseB + goff),
                (__attribute__((address_space(3))) void*)(Bs + w*512), 16, 0, 0);
        }
        __syncthreads();
        #pragma unroll
        for (int kk = 0; kk < 2; ++kk) {
            f16x8 af[4], bfr[4];
            #pragma unroll
            for (int i = 0; i < 4; ++i)
                af[i] = *(const f16x8*)&As[((wm*8 + i*2 + kk)*64 + (lane>>4)*16 + (lane&15))*8];
            #pragma unroll
            for (int j = 0; j < 4; ++j)
                bfr[j] = *(const f16x8*)&Bs[((wn*8 + j*2 + kk)*64 + (lane>>4)*16 + (lane&15))*8];
            #pragma unroll
            for (int i = 0; i < 4; ++i)
                #pragma unroll
                for (int j = 0; j < 4; ++j)
                    acc[i][j] = __builtin_amdgcn_mfma_f32_16x16x32_f16(af[i], bfr[j], acc[i][j], 0, 0, 0);
        }
        __syncthreads();
    }
    if (MODE == 0) {
        #pragma unroll
        for (int i = 0; i < 4; ++i) {
            int m = bm + wm*64 + i*16 + (lane>>4)*4;
            #pragma unroll
            for (int j = 0; j < 4; ++j) {
                int col = bn + wn*64 + j*16 + (lane&15);
                #pragma unroll
                for (int rg = 0; rg < 4; ++rg)
                    P[(size_t)(m + rg)*DIDIM + col] = (_Float16)acc[i][j][rg];
            }
        }
    } else {
        float bfv[4];
        #pragma unroll
        for (int j = 0; j < 4; ++j) bfv[j] = bf[bn + wn*64 + j*16 + (lane&15)];
        #pragma unroll
        for (int i = 0; i < 4; ++i) {
            #pragma unroll
            for (int rg = 0; rg < 4; ++rg) {
                float s = 0.f;
                #pragma unroll
                for (int j = 0; j < 4; ++j) {
                    float q = acc[i][j][rg];
                    s += q * (q + 2.f*bfv[j]);
                }
                s += __shfl_xor(s, 1, 64);
                s += __shfl_xor(s, 2, 64);
                s += __shfl_xor(s, 4, 64);
                s += __shfl_xor(s, 8, 64);
                if ((lane & 15) == 0) {
                    int row = bm + wm*64 + i*16 + (lane>>4)*4 + rg;
                    knp[(size_t)(blockIdx.y*2 + wn)*NP + row] = s;
                }
            }
        }
    }
}

// ---------- finalize kinorm: bf-norm + 4 partials; INF for pad rows ----------
__global__ __launch_bounds__(256) void k_norm_fin(
    const float* __restrict__ knp, const float* __restrict__ bf, float* __restrict__ kinorm)
{
    int n = blockIdx.x*256 + threadIdx.x;
    kinorm[n] = (n < NTOT)
        ? bf[256] + knp[n] + knp[(size_t)NP + n] + knp[(size_t)2*NP + n] + knp[(size_t)3*NP + n]
        : INFINITY;
}

// ---------- K3: MFMA score GEMM, f16 keys out (conflict-free permuted-source LDS) ----------
__global__ __launch_bounds__(256) void k_dist_mfma(
    const _Float16* __restrict__ kp2, const _Float16* __restrict__ cand2,
    const float* __restrict__ kinorm, _Float16* __restrict__ sb)
{
    __shared__ __align__(16) _Float16 As[128*64];
    __shared__ __align__(16) _Float16 Bs[128*64];
    int tid = threadIdx.x;
    int lane = tid & 63, wv = tid >> 6;
    int wm = wv >> 1, wn = wv & 1;
    int bm = blockIdx.x * 128;
    int bn = blockIdx.y * 128;
    f32x4 acc[4][4] = {};
    const size_t baseA = (size_t)bm * 384;
    const size_t baseB = (size_t)bn * 384;
    for (int kt = 0; kt < 6; ++kt) {
        #pragma unroll
        for (int r = 0; r < 4; ++r) {
            int w = wv*4 + r;
            int s = w*64 + lane;
            int rl = s & 15;
            int q  = (s >> 4) & 3;
            int kk2= (s >> 6) & 1;
            int ii = (s >> 7) & 3;
            int wq = (s >> 9) & 1;
            size_t goff = (size_t)(wq*64 + ii*16 + rl)*384 + kt*64 + (kk2*4 + q)*8;
            __builtin_amdgcn_global_load_lds(
                (const __attribute__((address_space(1))) void*)(kp2 + baseA + goff),
                (__attribute__((address_space(3))) void*)(As + w*512), 16, 0, 0);
            __builtin_amdgcn_global_load_lds(
                (const __attribute__((address_space(1))) void*)(cand2 + baseB + goff),
                (__attribute__((address_space(3))) void*)(Bs + w*512), 16, 0, 0);
        }
        __syncthreads();
        #pragma unroll
        for (int kk = 0; kk < 2; ++kk) {
            f16x8 af[4], bfr[4];
            #pragma unroll
            for (int i = 0; i < 4; ++i)
                af[i] = *(const f16x8*)&As[((wm*8 + i*2 + kk)*64 + (lane>>4)*16 + (lane&15))*8];
            #pragma unroll
            for (int j = 0; j < 4; ++j)
                bfr[j] = *(const f16x8*)&Bs[((wn*8 + j*2 + kk)*64 + (lane>>4)*16 + (lane&15))*8];
            #pragma unroll
            for (int i = 0; i < 4; ++i)
                #pragma unroll
                for (int j = 0; j < 4; ++j)
                    acc[i][j] = __builtin_amdgcn_mfma_f32_16x16x32_f16(af[i], bfr[j], acc[i][j], 0, 0, 0);
        }
        __syncthreads();
    }
    #pragma unroll
    for (int i = 0; i < 4; ++i) {
        int m = bm + wm*64 + i*16 + (lane>>4)*4;
        #pragma unroll
        for (int j = 0; j < 4; ++j) {
            int nl = bn + wn*64 + j*16 + (lane&15);
            float kn = kinorm[nl];
            #pragma unroll
            for (int rg = 0; rg < 4; ++rg)
                sb[(size_t)(m + rg)*NP + nl] = (_Float16)fmaxf(kn - 2.f*acc[i][j][rg], 0.f);
        }
    }
}

// ---------- K4a: zero histograms + counters ----------
__global__ __launch_bounds__(256) void k_zero(unsigned* __restrict__ hist, int* __restrict__ cnt)
{
    int b = blockIdx.x, t = threadIdx.x;
    #pragma unroll
    for (int i = 0; i < 4; ++i) hist[(size_t)b*1024 + t + i*256] = 0;
    if (t == 0) cnt[b] = 0;
}

// ---------- K4b: per-row 1024-bin histogram of f16 keys (u16 monotone) ----------
__global__ __launch_bounds__(256) void k_hist(
    const unsigned short* __restrict__ sb, unsigned* __restrict__ hist)
{
    __shared__ unsigned hloc[2][1024];
    int b = blockIdx.x, seg = blockIdx.y, tid = threadIdx.x;
    #pragma unroll
    for (int i = 0; i < 4; ++i) { hloc[0][tid + i*256] = 0; hloc[1][tid + i*256] = 0; }
    __syncthreads();
    const unsigned short* row = sb + (size_t)b*NP + (size_t)seg*SEG;
    unsigned* hs = hloc[tid & 1];
    for (int base = 0; base < SEG; base += 2048) {
        int j = base + tid*8;
        if (j < SEG) {
            uint4 u = *(const uint4*)(row + j);
            atomicAdd(&hs[(u.x & 0xffffu) >> 6], 1u);
            atomicAdd(&hs[(u.x >> 16) >> 6], 1u);
            atomicAdd(&hs[(u.y & 0xffffu) >> 6], 1u);
            atomicAdd(&hs[(u.y >> 16) >> 6], 1u);
            atomicAdd(&hs[(u.z & 0xffffu) >> 6], 1u);
            atomicAdd(&hs[(u.z >> 16) >> 6], 1u);
            atomicAdd(&hs[(u.w & 0xffffu) >> 6], 1u);
            atomicAdd(&hs[(u.w >> 16) >> 6], 1u);
        }
    }
    __syncthreads();
    #pragma unroll
    for (int i = 0; i < 4; ++i) {
        int bin = tid + i*256;
        unsigned v = hloc[0][bin] + hloc[1][bin];
        if (v) atomicAdd(&hist[(size_t)b*1024 + bin], v);
    }
}

// ---------- K4c: prefix-scan histogram, pick threshold bits (cum >= 96) ----------
__global__ __launch_bounds__(256) void k_hscan(
    const unsigned* __restrict__ hist, int* __restrict__ Tb)
{
    __shared__ unsigned p[256];
    __shared__ int tstar;
    int b = blockIdx.x, tid = threadIdx.x;
    const unsigned* h = hist + (size_t)b*1024;
    unsigned s0 = h[tid*4], s1 = h[tid*4+1], s2 = h[tid*4+2], s3 = h[tid*4+3];
    unsigned tot = s0 + s1 + s2 + s3;
    p[tid] = tot;
    if (tid == 0) tstar = 1023;
    __syncthreads();
    for (int off = 1; off < 256; off <<= 1) {
        unsigned t2 = (tid >= off) ? p[tid - off] : 0;
        __syncthreads();
        p[tid] += t2;
        __syncthreads();
    }
    unsigned c = p[tid] - tot;
    int found = -1;
    c += s0; if (c >= CTX) found = tid*4;
    if (found < 0) { c += s1; if (c >= CTX) found = tid*4+1; }
    if (found < 0) { c += s2; if (c >= CTX) found = tid*4+2; }
    if (found < 0) { c += s3; if (c >= CTX) found = tid*4+3; }
    if (found >= 0) atomicMin(&tstar, found);
    __syncthreads();
    if (tid == 0) Tb[b] = (tstar << 6) | 63;
}

// ---------- K4d: compact survivors (u16 key <= Tb) ----------
__global__ __launch_bounds__(256) void k_compact(
    const unsigned short* __restrict__ sb, const int* __restrict__ Tb,
    int* __restrict__ cnt, int* __restrict__ candI)
{
    int b = blockIdx.x, seg = blockIdx.y, tid = threadIdx.x;
    unsigned tb = (unsigned)Tb[b];
    const unsigned short* row = sb + (size_t)b*NP + (size_t)seg*SEG;
    int nbase = seg*SEG;
    for (int base = 0; base < SEG; base += 2048) {
        int j = base + tid*8;
        if (j < SEG) {
            uint4 u = *(const uint4*)(row + j);
            unsigned e[8] = { u.x & 0xffffu, u.x >> 16, u.y & 0xffffu, u.y >> 16,
                              u.z & 0xffffu, u.z >> 16, u.w & 0xffffu, u.w >> 16 };
            #pragma unroll
            for (int q = 0; q < 8; ++q) {
                if (e[q] <= tb) {
                    int p2 = atomicAdd(&cnt[b], 1);
                    if (p2 < CAP) candI[(size_t)b*CAP + p2] = nbase + j + q;
                }
            }
        }
    }
}

// ---------- K4e: exact fp32 rescore of survivors + bitonic top-96 ----------
__global__ __launch_bounds__(256) void k_resc(
    const float* __restrict__ kp, const float* __restrict__ cand,
    const float* __restrict__ kinorm, const int* __restrict__ cnt,
    const int* __restrict__ candI,
    float* __restrict__ finV, int* __restrict__ finI)
{
    __shared__ float kps[FDIM];
    __shared__ float sval[2048];
    __shared__ int   sidx[2048];
    int b = blockIdx.x, tid = threadIdx.x, lane = tid & 63, wv = tid >> 6;
    if (tid < FDIM) kps[tid] = kp[(size_t)b*FDIM + tid];
    if (tid < 128) { sval[tid] = INFINITY; sidx[tid] = 0x7fffffff; }
    int nc = cnt[b]; if (nc > CAP) nc = CAP;
    __syncthreads();
    for (int c0 = 0; c0 < nc; c0 += 1920) {
        int m = nc - c0; if (m > 1920) m = 1920;
        for (int c = wv; c < m; c += 4) {
            int n = candI[(size_t)b*CAP + c0 + c];
            float2 v = *(const float2*)(cand + (size_t)n*FDIM + lane*2);
            float p = v.x*kps[lane*2] + v.y*kps[lane*2+1];
            for (int off = 32; off; off >>= 1) p += __shfl_xor(p, off, 64);
            if (lane == 0) { sval[128 + c] = kinorm[n] - 2.f*p; sidx[128 + c] = n; }
        }
        __syncthreads();
        int nv = 128 + m;
        int size = 256; while (size < nv) size <<= 1;
        for (int i2 = nv + tid; i2 < size; i2 += 256) { sval[i2] = INFINITY; sidx[i2] = 0x7fffffff; }
        __syncthreads();
        for (int k2 = 2; k2 <= size; k2 <<= 1) {
            for (int jj = k2 >> 1; jj > 0; jj >>= 1) {
                for (int i = tid; i < size; i += 256) {
                    int ix = i ^ jj;
                    if (ix > i) {
                        bool up = ((i & k2) == 0);
                        float a = sval[i], b2 = sval[ix];
                        int ia = sidx[i], ib = sidx[ix];
                        bool gt = (a > b2) || (a == b2 && ia > ib);
                        if (gt == up) {
                            sval[i] = b2; sval[ix] = a;
                            sidx[i] = ib; sidx[ix] = ia;
                        }
                    }
                }
                __syncthreads();
            }
        }
    }
    if (tid < CTX) { finV[(size_t)b*CTX + tid] = sval[tid]; finI[(size_t)b*CTX + tid] = sidx[tid]; }
}

// ---------- K5: softmax weights over selected scores + weighted y ----------
__global__ __launch_bounds__(128) void k_weights(
    const float* __restrict__ finV, const int* __restrict__ finI,
    const float* __restrict__ candy, float* __restrict__ wts, float* __restrict__ wy)
{
    __shared__ float sh[128];
    int b = blockIdx.x, t = threadIdx.x;
    float v = (t < CTX) ? finV[b*CTX + t] : -INFINITY;
    sh[t] = v; __syncthreads();
    for (int s2 = 64; s2 > 0; s2 >>= 1) { if (t < s2) sh[t] = fmaxf(sh[t], sh[t+s2]); __syncthreads(); }
    float m = sh[0]; __syncthreads();
    float e = (t < CTX) ? expf(v - m) : 0.f;
    sh[t] = e; __syncthreads();
    for (int s2 = 64; s2 > 0; s2 >>= 1) { if (t < s2) sh[t] += sh[t+s2]; __syncthreads(); }
    float w = e / sh[0]; __syncthreads();
    if (t < CTX) wts[b*CTX + t] = w;
    float yv = (t < CTX) ? candy[finI[b*CTX + t]] : 0.f;
    sh[t] = w * yv; __syncthreads();
    for (int s2 = 64; s2 > 0; s2 >>= 1) { if (t < s2) sh[t] += sh[t+s2]; __syncthreads(); }
    if (t == 0) wy[b] = sh[0];
}

// ---------- K6: Hw[b][j] = sum_c w_c * relu(xP[b][j] - P[idx_c][j]) ----------
__global__ __launch_bounds__(256) void k_vgather(
    const float* __restrict__ xP, const _Float16* __restrict__ P,
    const int* __restrict__ finI, const float* __restrict__ wts,
    float* __restrict__ Hw)
{
    __shared__ float wsh[CTX];
    __shared__ int   idx[CTX];
    int b = blockIdx.x, tid = threadIdx.x;
    if (tid < CTX) { idx[tid] = finI[b*CTX + tid]; wsh[tid] = wts[b*CTX + tid]; }
    __syncthreads();
    int c0 = tid*2;
    float x0 = xP[(size_t)b*DIDIM + c0];
    float x1 = xP[(size_t)b*DIDIM + c0 + 1];
    float a0 = 0.f, a1 = 0.f;
    for (int c = 0; c < CTX; ++c) {
        size_t base = (size_t)idx[c]*DIDIM + c0;
        float w = wsh[c];
        f16x2 pv = *(const f16x2*)(P + base);
        a0 += w * fmaxf(x0 - (float)pv[0], 0.f);
        a1 += w * fmaxf(x1 - (float)pv[1], 0.f);
    }
    float2 r; r.x = a0; r.y = a1;
    *(float2*)(Hw + (size_t)b*DIDIM + c0) = r;
}

// ---------- K7: V assembly + residual + LN + MLP + LN + head ----------
__global__ __launch_bounds__(256) void k_final(
    const float* __restrict__ xenc, const float* __restrict__ Hw,
    const float* __restrict__ wy,
    const float* __restrict__ WY, const float* __restrict__ bY,
    const float* __restrict__ WT2,
    const float* __restrict__ lpg, const float* __restrict__ lpb,
    const float* __restrict__ WP1, const float* __restrict__ bP1,
    const float* __restrict__ WP2, const float* __restrict__ bP2,
    const float* __restrict__ logg, const float* __restrict__ lob,
    const float* __restrict__ Wout, const float* __restrict__ bout,
    float* __restrict__ out)
{
    __shared__ float hs[DIDIM];
    __shared__ float xs[DDIM];
    __shared__ float red[256];
    int b = blockIdx.x, j = threadIdx.x;
    hs[j] = Hw[(size_t)b*DIDIM + j];
    hs[j+256] = Hw[(size_t)b*DIDIM + j + 256];
    __syncthreads();
    float v = wy[b] * WY[j] + bY[j];
    for (int d = 0; d < DIDIM; ++d) v += hs[d] * WT2[d*DDIM + j];
    float x = xenc[(size_t)b*DDIM + j] + v;
    red[j] = x; __syncthreads();
    for (int s2 = 128; s2 > 0; s2 >>= 1) { if (j < s2) red[j] += red[j+s2]; __syncthreads(); }
    float mean = red[0] * (1.f/DDIM); __syncthreads();
    float xc = x - mean;
    red[j] = xc*xc; __syncthreads();
    for (int s2 = 128; s2 > 0; s2 >>= 1) { if (j < s2) red[j] += red[j+s2]; __syncthreads(); }
    float rstd = 1.f / sqrtf(red[0]*(1.f/DDIM) + 1e-5f); __syncthreads();
    xs[j] = xc * rstd * lpg[j] + lpb[j];
    __syncthreads();
    float u0 = bP1[j], u1 = bP1[j+256];
    for (int d = 0; d < DDIM; ++d) {
        float hd = xs[d];
        u0 += hd * WP1[d*DIDIM + j];
        u1 += hd * WP1[d*DIDIM + j + 256];
    }
    __syncthreads();
    hs[j] = fmaxf(u0, 0.f); hs[j+256] = fmaxf(u1, 0.f);
    __syncthreads();
    float x2 = x + bP2[j];
    for (int d = 0; d < DIDIM; ++d) x2 += hs[d] * WP2[d*DDIM + j];
    red[j] = x2; __syncthreads();
    for (int s2 = 128; s2 > 0; s2 >>= 1) { if (j < s2) red[j] += red[j+s2]; __syncthreads(); }
    float mean2 = red[0] * (1.f/DDIM); __syncthreads();
    float xc2 = x2 - mean2;
    red[j] = xc2*xc2; __syncthreads();
    for (int s2 = 128; s2 > 0; s2 >>= 1) { if (j < s2) red[j] += red[j+s2]; __syncthreads(); }
    float rstd2 = 1.f / sqrtf(red[0]*(1.f/DDIM) + 1e-5f); __syncthreads();
    float r = fmaxf(xc2 * rstd2 * logg[j] + lob[j], 0.f);
    red[j] = r * Wout[j]; __syncthreads();
    for (int s2 = 128; s2 > 0; s2 >>= 1) { if (j < s2) red[j] += red[j+s2]; __syncthreads(); }
    if (j == 0) out[b] = red[0] + bout[0];
}

extern "C" void kernel_launch(void* const* d_in, const int* in_sizes, int n_in,
                              void* d_out, int out_size, void* d_ws, size_t ws_size,
                              hipStream_t stream)
{
    (void)in_sizes; (void)n_in; (void)out_size; (void)ws_size;
    const float* x_num = (const float*)d_in[0];
    const float* cand  = (const float*)d_in[1];
    const float* candy = (const float*)d_in[2];
    const float* Wlin  = (const float*)d_in[3];
    const float* blin  = (const float*)d_in[4];
    const float* WK    = (const float*)d_in[5];
    const float* bK    = (const float*)d_in[6];
    const float* WY    = (const float*)d_in[7];
    const float* bY    = (const float*)d_in[8];
    const float* WT1   = (const float*)d_in[9];
    const float* bT1   = (const float*)d_in[10];
    const float* WT2   = (const float*)d_in[11];
    const float* lpg   = (const float*)d_in[12];
    const float* lpb   = (const float*)d_in[13];
    const float* WP1   = (const float*)d_in[14];
    const float* bP1   = (const float*)d_in[15];
    const float* WP2   = (const float*)d_in[16];
    const float* bP2   = (const float*)d_in[17];
    const float* logg  = (const float*)d_in[18];
    const float* lob   = (const float*)d_in[19];
    const float* Wout  = (const float*)d_in[20];
    const float* bout  = (const float*)d_in[21];
    float* out = (float*)d_out;

    float* ws = (float*)d_ws;
    size_t o = 0;
    float* Wf     = ws + o; o += (size_t)FDIM*DDIM;
    float* bf     = ws + o; o += 320;                  // [256] holds ||bf||^2
    float* WfT1   = ws + o; o += (size_t)FDIM*DIDIM;
    float* xenc   = ws + o; o += (size_t)BQ*DDIM;
    float* kq     = ws + o; o += (size_t)BQ*DDIM;
    float* kp     = ws + o; o += (size_t)BQ*FDIM;
    float* kinorm = ws + o; o += NP;
    float* knp    = ws + o; o += (size_t)4*NP;
    float* finV   = ws + o; o += (size_t)BQ*CTX;
    int*   finI   = (int*)(ws + o); o += (size_t)BQ*CTX;
    float* wts    = ws + o; o += (size_t)BQ*CTX;
    float* wy     = ws + o; o += BQ;
    float* Hw     = ws + o; o += (size_t)BQ*DIDIM;
    float* xP     = ws + o; o += (size_t)BQ*DIDIM;
    _Float16* kp2 = (_Float16*)(ws + o); o += (size_t)BQ*384/2;
    _Float16* c2  = (_Float16*)(ws + o); o += (size_t)NP*384/2;
    _Float16* Wsp = (_Float16*)(ws + o); o += (size_t)768*384/2;
    unsigned* hist= (unsigned*)(ws + o); o += (size_t)BH*1024;
    int*   cnt    = (int*)(ws + o); o += BH;
    int*   Tb     = (int*)(ws + o); o += BH;
    int*   candI  = (int*)(ws + o); o += (size_t)BH*CAP;
    _Float16* sb  = (_Float16*)(ws + o); o += (size_t)BH*NP/2;   // aliased: P = sb (NP*512 f16 == BH*NP f16)
    _Float16* P   = sb;

    k_fuse<<<dim3(FDIM+1), dim3(256), 0, stream>>>(Wlin, blin, WK, bK, Wf, bf);
    k_fuse2<<<dim3(FDIM), dim3(256), 0, stream>>>(Wf, WT1, WfT1);
    k_cvt_w<<<dim3(DDIM+DIDIM), dim3(128), 0, stream>>>(Wf, WfT1, Wsp);
    k_query<<<dim3(BQ), dim3(256), 0, stream>>>(x_num, Wlin, blin, Wf, bf, xenc, kq);
    k_kp<<<dim3(BQ), dim3(128), 0, stream>>>(kq, Wf, kp);
    k_xp<<<dim3(BQ), dim3(256), 0, stream>>>(x_num, WfT1, bT1, xP);
    k_cvt_kp<<<dim3(BQ*FDIM/4/256), dim3(256), 0, stream>>>(kp, kp2);
    k_cvt_cand<<<dim3(NP*FDIM/4/256), dim3(256), 0, stream>>>(cand, c2);

    // kinorm via split-f16 MFMA: q = cand@Wf, kinorm = ||q||^2 + 2 bf.q + ||bf||^2
    k_csplit<1><<<dim3(NP/128, DDIM/128), dim3(256), 0, stream>>>(c2, Wsp, (_Float16*)nullptr, knp, bf);
    k_norm_fin<<<dim3(NP/256), dim3(256), 0, stream>>>(knp, bf, kinorm);

    for (int bh = 0; bh < 2; ++bh) {
        const _Float16* kp2h = kp2 + (size_t)bh*BH*384;
        const float* kph = kp + (size_t)bh*BH*FDIM;
        float* finVh = finV + (size_t)bh*BH*CTX;
        int*   finIh = finI + (size_t)bh*BH*CTX;
        k_zero<<<dim3(BH), dim3(256), 0, stream>>>(hist, cnt);
        k_dist_mfma<<<dim3(BH/128, NP/128), dim3(256), 0, stream>>>(kp2h, c2, kinorm, sb);
        k_hist<<<dim3(BH, 4), dim3(256), 0, stream>>>((const unsigned short*)sb, hist);
        k_hscan<<<dim3(BH), dim3(256), 0, stream>>>(hist, Tb);
        k_compact<<<dim3(BH, 4), dim3(256), 0, stream>>>((const unsigned short*)sb, Tb, cnt, candI);
        k_resc<<<dim3(BH), dim3(256), 0, stream>>>(kph, cand, kinorm, cnt, candI, finVh, finIh);
    }

    k_weights<<<dim3(BQ), dim3(128), 0, stream>>>(finV, finI, candy, wts, wy);

    // P = cand @ WfT1 (f16 out), overwrites sb after its last read
    k_csplit<0><<<dim3(NP/128, DIDIM/128), dim3(256), 0, stream>>>(c2, Wsp + (size_t)DDIM*384, P, (float*)nullptr, (const float*)nullptr);
    k_vgather<<<dim3(BQ), dim3(256), 0, stream>>>(xP, P, finI, wts, Hw);
    k_final<<<dim3(BQ), dim3(256), 0, stream>>>(xenc, Hw, wy, WY, bY, WT2,
                                                lpg, lpb, WP1, bP1, WP2, bP2,
                                                logg, lob, Wout, bout, out);
}